// Round 1
// baseline (2916.581 us; speedup 1.0000x reference)
//
#include <hip/hip_runtime.h>

// ---------------------------------------------------------------------------
// GCN encoder, 2 layers, N=100000 D=H=128, E=1.6M.
// Round 1: correctness-first. fp32 tiled GEMM + atomicAdd edge scatter.
// ---------------------------------------------------------------------------

__global__ __launch_bounds__(256) void k_init_deg(float* deg, int n) {
    int i = blockIdx.x * 256 + threadIdx.x;
    if (i < n) deg[i] = 1.0f;   // self-loop weight
}

__global__ __launch_bounds__(256) void k_deg_acc(float* deg, const float* __restrict__ w,
                                                 const int* __restrict__ dst, int e) {
    int i = blockIdx.x * 256 + threadIdx.x;
    if (i < e) atomicAdd(&deg[dst[i]], w[i]);
}

__global__ __launch_bounds__(256) void k_dis(float* dis, float* selfc, int n) {
    int i = blockIdx.x * 256 + threadIdx.x;
    if (i < n) {
        float d = dis[i];            // deg >= 1 always (self-loop + nonneg weights)
        float r = rsqrtf(d);
        dis[i] = r;
        selfc[i] = r * r;            // 1/deg
    }
}

__global__ __launch_bounds__(256) void k_norm(float* __restrict__ norm,
                                              const float* __restrict__ dis,
                                              const float* __restrict__ w,
                                              const int* __restrict__ src,
                                              const int* __restrict__ dst, int e) {
    int i = blockIdx.x * 256 + threadIdx.x;
    if (i < e) norm[i] = dis[src[i]] * w[i] * dis[dst[i]];
}

// C[row, 0..127] = A[row, 0..127] @ W[128,128].  A row-stride lda, C row-stride ldc.
// Block: 256 threads -> 64 rows x 128 cols tile. Thread (ty,tx): 4 rows x 8 cols.
__global__ __launch_bounds__(256) void k_gemm(const float* __restrict__ A, int lda,
                                              const float* __restrict__ W,
                                              float* __restrict__ C, int ldc, int n) {
    __shared__ float As[64][68];    // +4 pad: 16B-aligned rows, 2-way-max bank alias
    __shared__ float Ws[64][128];

    const int t = threadIdx.x;
    const int ty = t >> 4;          // 0..15 -> rows ty*4..+3
    const int tx = t & 15;          // 0..15 -> cols tx*8..+7
    const int row0 = blockIdx.x * 64;

    float acc[4][8];
#pragma unroll
    for (int i = 0; i < 4; i++)
#pragma unroll
        for (int j = 0; j < 8; j++) acc[i][j] = 0.f;

    for (int kc = 0; kc < 128; kc += 64) {
        // stage A tile: thread t loads 16 floats of row (t>>2), col seg (t&3)*16
        {
            const int lr = t >> 2, q = t & 3;
            const int gr = row0 + lr;
            float4 v0, v1, v2, v3;
            if (gr < n) {
                const float4* ap = (const float4*)(A + (size_t)gr * lda + kc + q * 16);
                v0 = ap[0]; v1 = ap[1]; v2 = ap[2]; v3 = ap[3];
            } else {
                v0 = v1 = v2 = v3 = make_float4(0.f, 0.f, 0.f, 0.f);
            }
            float4* asp = (float4*)&As[lr][q * 16];
            asp[0] = v0; asp[1] = v1; asp[2] = v2; asp[3] = v3;
        }
        // stage W chunk: rows kc..kc+63, all 128 cols
        {
            const int wr = t >> 2, q = t & 3;
            const float4* wp = (const float4*)(W + (size_t)(kc + wr) * 128 + q * 32);
            float4* wd = (float4*)&Ws[wr][q * 32];
#pragma unroll
            for (int u = 0; u < 8; u++) wd[u] = wp[u];
        }
        __syncthreads();

#pragma unroll 8
        for (int k = 0; k < 64; k++) {
            float a[4];
#pragma unroll
            for (int i = 0; i < 4; i++) a[i] = As[ty * 4 + i][k];
            float4 w0 = *(const float4*)&Ws[k][tx * 8];
            float4 w1 = *(const float4*)&Ws[k][tx * 8 + 4];
            float w[8] = {w0.x, w0.y, w0.z, w0.w, w1.x, w1.y, w1.z, w1.w};
#pragma unroll
            for (int i = 0; i < 4; i++)
#pragma unroll
                for (int j = 0; j < 8; j++) acc[i][j] += a[i] * w[j];
        }
        __syncthreads();
    }

#pragma unroll
    for (int i = 0; i < 4; i++) {
        int gr = row0 + ty * 4 + i;
        if (gr < n) {
            float4* cp = (float4*)(C + (size_t)gr * ldc + tx * 8);
            cp[0] = make_float4(acc[i][0], acc[i][1], acc[i][2], acc[i][3]);
            cp[1] = make_float4(acc[i][4], acc[i][5], acc[i][6], acc[i][7]);
        }
    }
}

// agg[node, c] = selfc[node] * hW[node, c]   (full overwrite -> poison-safe init)
__global__ __launch_bounds__(256) void k_init_agg(float* __restrict__ agg,
                                                  const float* __restrict__ hW, int ldh,
                                                  const float* __restrict__ selfc, long total) {
    long i = (long)blockIdx.x * 256 + threadIdx.x;
    if (i < total) {
        long node = i >> 7;
        int c = (int)(i & 127);
        agg[i] = selfc[node] * hW[node * ldh + c];
    }
}

// one wavefront per edge: lane l handles features 2l, 2l+1
__global__ __launch_bounds__(256) void k_edge_agg(const float* __restrict__ hW, int ldh,
                                                  float* __restrict__ agg,  // ld 128
                                                  const float* __restrict__ norm,
                                                  const int* __restrict__ src,
                                                  const int* __restrict__ dst, int e) {
    int wid = blockIdx.x * 4 + (threadIdx.x >> 6);
    int lane = threadIdx.x & 63;
    if (wid >= e) return;
    int s = src[wid], d = dst[wid];
    float nm = norm[wid];
    float2 v = *(const float2*)(hW + (size_t)s * ldh + lane * 2);
    float* ap = agg + (size_t)d * 128 + lane * 2;
    atomicAdd(ap, nm * v.x);
    atomicAdd(ap + 1, nm * v.y);
}

// outbase[node*256 + c] = relu(agg[node,c] + b[c])
__global__ __launch_bounds__(256) void k_final(float* __restrict__ outbase,
                                               const float* __restrict__ agg,
                                               const float* __restrict__ b, long total) {
    long i = (long)blockIdx.x * 256 + threadIdx.x;
    if (i < total) {
        long node = i >> 7;
        int c = (int)(i & 127);
        float v = agg[i] + b[c];
        outbase[node * 256 + c] = v > 0.f ? v : 0.f;
    }
}

extern "C" void kernel_launch(void* const* d_in, const int* in_sizes, int n_in,
                              void* d_out, int out_size, void* d_ws, size_t ws_size,
                              hipStream_t stream) {
    const float* x  = (const float*)d_in[0];
    const float* ew = (const float*)d_in[1];
    const float* W0 = (const float*)d_in[2];
    const float* b0 = (const float*)d_in[3];
    const float* W1 = (const float*)d_in[4];
    const float* b1 = (const float*)d_in[5];
    const int*   ei = (const int*)d_in[6];

    const int N = in_sizes[0] / 128;
    const int E = in_sizes[1];
    const int* src = ei;        // edge_index row 0
    const int* dst = ei + E;    // edge_index row 1
    float* out = (float*)d_out; // [N, 256]

    // workspace layout (floats): dis[N] | selfc[N] | norm[E] | agg[N*128]
    float* dis   = (float*)d_ws;
    float* selfc = dis + N;
    float* norm  = selfc + N;
    float* agg   = norm + E;

    // hW lives in the not-yet-final half of d_out: cols 128..255, row stride 256
    float* hW = out + 128;

    const long tot = (long)N * 128;
    const int gN = (N + 255) / 256;
    const int gE = (E + 255) / 256;
    const int gT = (int)((tot + 255) / 256);
    const int gG = (N + 63) / 64;
    const int gW = (E + 3) / 4;

    // ---- normalization precompute ----
    k_init_deg<<<gN, 256, 0, stream>>>(dis, N);
    k_deg_acc<<<gE, 256, 0, stream>>>(dis, ew, dst, E);
    k_dis<<<gN, 256, 0, stream>>>(dis, selfc, N);
    k_norm<<<gE, 256, 0, stream>>>(norm, dis, ew, src, dst, E);

    // ---- layer 1: h1 -> out cols [0,128) ----
    k_gemm<<<gG, 256, 0, stream>>>(x, 128, W0, hW, 256, N);
    k_init_agg<<<gT, 256, 0, stream>>>(agg, hW, 256, selfc, tot);
    k_edge_agg<<<gW, 256, 0, stream>>>(hW, 256, agg, norm, src, dst, E);
    k_final<<<gT, 256, 0, stream>>>(out, agg, b0, tot);

    // ---- layer 2: h2 -> out cols [128,256) ----
    k_gemm<<<gG, 256, 0, stream>>>(out, 256, W1, hW, 256, N);   // reads cols 0..127, writes cols 128..255
    k_init_agg<<<gT, 256, 0, stream>>>(agg, hW, 256, selfc, tot);
    k_edge_agg<<<gW, 256, 0, stream>>>(hW, 256, agg, norm, src, dst, E);
    k_final<<<gT, 256, 0, stream>>>(out + 128, agg, b1, tot);
}

// Round 2
// 607.988 us; speedup vs baseline: 4.7971x; 4.7971x over previous
//
#include <hip/hip_runtime.h>

// ---------------------------------------------------------------------------
// GCN encoder, 2 layers, N=100000 D=H=128, E=1.6M.
// Round 2: atomic-free aggregation via on-device CSR-by-dst build.
//   precompute: deg+count hist -> rsqrt -> exclusive scan -> scatter (src,norm)
//   per layer:  gemm (fp32 tiled) -> fused {self + CSR-gather-accumulate +
//               bias + relu} writing d_out once (no agg buffer, no atomics).
// ws layout (4B words): dis[N] | cursor[N] | es[E] | en[E] | hW[N*128] | sums[512]
//   cursor: histogram -> exclusive scan in place -> scatter cursors; after the
//   scatter it holds row END pointers (rowptr[d+1]) -- the classic trick.
// ---------------------------------------------------------------------------

__global__ __launch_bounds__(256) void k_init(float* deg, int* cnt, int n) {
    int i = blockIdx.x * 256 + threadIdx.x;
    if (i < n) { deg[i] = 1.0f; cnt[i] = 0; }   // self-loop weight = 1
}

__global__ __launch_bounds__(256) void k_hist(float* deg, int* cnt,
                                              const float* __restrict__ w,
                                              const int* __restrict__ dst, int e) {
    int i = blockIdx.x * 256 + threadIdx.x;
    if (i < e) {
        int d = dst[i];
        atomicAdd(&deg[d], w[i]);
        atomicAdd(&cnt[d], 1);
    }
}

__global__ __launch_bounds__(256) void k_dis(float* dis, int n) {
    int i = blockIdx.x * 256 + threadIdx.x;
    if (i < n) dis[i] = rsqrtf(dis[i]);   // deg >= 1 always
}

// ---- exclusive scan over cnt[N] (3-phase, N=100000 -> 391 blocks) ----
__global__ __launch_bounds__(256) void k_scan1(int* data, int* sums, int n) {
    __shared__ int tmp[256];
    int gid = blockIdx.x * 256 + threadIdx.x;
    int v = (gid < n) ? data[gid] : 0;
    tmp[threadIdx.x] = v;
    __syncthreads();
    for (int off = 1; off < 256; off <<= 1) {
        int t = (threadIdx.x >= off) ? tmp[threadIdx.x - off] : 0;
        __syncthreads();
        tmp[threadIdx.x] += t;
        __syncthreads();
    }
    if (gid < n) data[gid] = tmp[threadIdx.x] - v;        // exclusive
    if (threadIdx.x == 255) sums[blockIdx.x] = tmp[255];  // block total
}

__global__ __launch_bounds__(512) void k_scan2(int* sums, int nb) {
    __shared__ int tmp[512];
    int v = (threadIdx.x < nb) ? sums[threadIdx.x] : 0;
    tmp[threadIdx.x] = v;
    __syncthreads();
    for (int off = 1; off < 512; off <<= 1) {
        int t = (threadIdx.x >= off) ? tmp[threadIdx.x - off] : 0;
        __syncthreads();
        tmp[threadIdx.x] += t;
        __syncthreads();
    }
    if (threadIdx.x < nb) sums[threadIdx.x] = tmp[threadIdx.x] - v;  // exclusive
}

__global__ __launch_bounds__(256) void k_scan3(int* data, const int* sums, int n) {
    int gid = blockIdx.x * 256 + threadIdx.x;
    if (gid < n) data[gid] += sums[blockIdx.x];
}

// scatter edges into dst-buckets; compute norm inline
__global__ __launch_bounds__(256) void k_scatter(const int* __restrict__ src,
                                                 const int* __restrict__ dst,
                                                 const float* __restrict__ ew,
                                                 const float* __restrict__ dis,
                                                 int* cursor, int* es, float* en, int e) {
    int i = blockIdx.x * 256 + threadIdx.x;
    if (i < e) {
        int s = src[i], d = dst[i];
        float nm = dis[s] * ew[i] * dis[d];
        int pos = atomicAdd(&cursor[d], 1);
        es[pos] = s;
        en[pos] = nm;
    }
}

// C[row, 0..127] = A[row, 0..127] @ W[128,128].
__global__ __launch_bounds__(256) void k_gemm(const float* __restrict__ A, int lda,
                                              const float* __restrict__ W,
                                              float* __restrict__ C, int ldc, int n) {
    __shared__ float As[64][68];
    __shared__ float Ws[64][128];

    const int t = threadIdx.x;
    const int ty = t >> 4;
    const int tx = t & 15;
    const int row0 = blockIdx.x * 64;

    float acc[4][8];
#pragma unroll
    for (int i = 0; i < 4; i++)
#pragma unroll
        for (int j = 0; j < 8; j++) acc[i][j] = 0.f;

    for (int kc = 0; kc < 128; kc += 64) {
        {
            const int lr = t >> 2, q = t & 3;
            const int gr = row0 + lr;
            float4 v0, v1, v2, v3;
            if (gr < n) {
                const float4* ap = (const float4*)(A + (size_t)gr * lda + kc + q * 16);
                v0 = ap[0]; v1 = ap[1]; v2 = ap[2]; v3 = ap[3];
            } else {
                v0 = v1 = v2 = v3 = make_float4(0.f, 0.f, 0.f, 0.f);
            }
            float4* asp = (float4*)&As[lr][q * 16];
            asp[0] = v0; asp[1] = v1; asp[2] = v2; asp[3] = v3;
        }
        {
            const int wr = t >> 2, q = t & 3;
            const float4* wp = (const float4*)(W + (size_t)(kc + wr) * 128 + q * 32);
            float4* wd = (float4*)&Ws[wr][q * 32];
#pragma unroll
            for (int u = 0; u < 8; u++) wd[u] = wp[u];
        }
        __syncthreads();

#pragma unroll 8
        for (int k = 0; k < 64; k++) {
            float a[4];
#pragma unroll
            for (int i = 0; i < 4; i++) a[i] = As[ty * 4 + i][k];
            float4 w0 = *(const float4*)&Ws[k][tx * 8];
            float4 w1 = *(const float4*)&Ws[k][tx * 8 + 4];
            float w[8] = {w0.x, w0.y, w0.z, w0.w, w1.x, w1.y, w1.z, w1.w};
#pragma unroll
            for (int i = 0; i < 4; i++)
#pragma unroll
                for (int j = 0; j < 8; j++) acc[i][j] += a[i] * w[j];
        }
        __syncthreads();
    }

#pragma unroll
    for (int i = 0; i < 4; i++) {
        int gr = row0 + ty * 4 + i;
        if (gr < n) {
            float4* cp = (float4*)(C + (size_t)gr * ldc + tx * 8);
            cp[0] = make_float4(acc[i][0], acc[i][1], acc[i][2], acc[i][3]);
            cp[1] = make_float4(acc[i][4], acc[i][5], acc[i][6], acc[i][7]);
        }
    }
}

// fused: out[d, c] = relu( dis[d]^2 * hW[d,c] + sum_j norm_j * hW[src_j, c] + b[c] )
// one wave per dst node; lane handles features {2*lane, 2*lane+1}.
__global__ __launch_bounds__(256) void k_agg(const float* __restrict__ hW,
                                             const int* __restrict__ es,
                                             const float* __restrict__ en,
                                             const int* __restrict__ endptr,
                                             const float* __restrict__ dis,
                                             const float* __restrict__ bias,
                                             float* __restrict__ outcol,  // stride 256
                                             int n) {
    int wid = blockIdx.x * 4 + (threadIdx.x >> 6);
    int lane = threadIdx.x & 63;
    if (wid >= n) return;

    int end   = endptr[wid];
    int start = (wid == 0) ? 0 : endptr[wid - 1];
    // wave-uniform in reality; make it provably uniform -> scalar loads in loop
    start = __builtin_amdgcn_readfirstlane(start);
    end   = __builtin_amdgcn_readfirstlane(end);

    float di = dis[wid];
    float2 h = *(const float2*)(hW + (size_t)wid * 128 + lane * 2);
    float2 acc;
    acc.x = di * di * h.x;
    acc.y = di * di * h.y;

    for (int j = start; j < end; ++j) {
        int s    = es[j];
        float nm = en[j];
        float2 v = *(const float2*)(hW + (size_t)s * 128 + lane * 2);
        acc.x += nm * v.x;
        acc.y += nm * v.y;
    }

    float2 b = *(const float2*)(bias + lane * 2);
    float2 o;
    o.x = fmaxf(acc.x + b.x, 0.f);
    o.y = fmaxf(acc.y + b.y, 0.f);
    *(float2*)(outcol + (size_t)wid * 256 + lane * 2) = o;
}

extern "C" void kernel_launch(void* const* d_in, const int* in_sizes, int n_in,
                              void* d_out, int out_size, void* d_ws, size_t ws_size,
                              hipStream_t stream) {
    const float* x  = (const float*)d_in[0];
    const float* ew = (const float*)d_in[1];
    const float* W0 = (const float*)d_in[2];
    const float* b0 = (const float*)d_in[3];
    const float* W1 = (const float*)d_in[4];
    const float* b1 = (const float*)d_in[5];
    const int*   ei = (const int*)d_in[6];

    const int N = in_sizes[0] / 128;
    const int E = in_sizes[1];
    const int* src = ei;
    const int* dst = ei + E;
    float* out = (float*)d_out;   // [N, 256]

    // ws layout (4B words)
    float* dis    = (float*)d_ws;
    int*   cursor = (int*)(dis + N);
    int*   es     = cursor + N;
    float* en     = (float*)(es + E);
    float* hW     = en + E;
    int*   sums   = (int*)(hW + (size_t)N * 128);

    const int gN = (N + 255) / 256;
    const int gE = (E + 255) / 256;
    const int gG = (N + 63) / 64;
    const int gA = (N + 3) / 4;       // 4 waves per block
    const int nb = gN;                // scan blocks (391)

    // ---- CSR build + normalization (once, reused by both layers) ----
    k_init<<<gN, 256, 0, stream>>>(dis, cursor, N);
    k_hist<<<gE, 256, 0, stream>>>(dis, cursor, ew, dst, E);
    k_dis<<<gN, 256, 0, stream>>>(dis, N);
    k_scan1<<<nb, 256, 0, stream>>>(cursor, sums, N);
    k_scan2<<<1, 512, 0, stream>>>(sums, nb);
    k_scan3<<<nb, 256, 0, stream>>>(cursor, sums, N);
    k_scatter<<<gE, 256, 0, stream>>>(src, dst, ew, dis, cursor, es, en, E);
    // cursor now holds row END pointers.

    // ---- layer 1: h1 -> out cols [0,128) ----
    k_gemm<<<gG, 256, 0, stream>>>(x, 128, W0, hW, 128, N);
    k_agg<<<gA, 256, 0, stream>>>(hW, es, en, cursor, dis, b0, out, N);

    // ---- layer 2: h2 -> out cols [128,256) ----
    k_gemm<<<gG, 256, 0, stream>>>(out, 256, W1, hW, 128, N);
    k_agg<<<gA, 256, 0, stream>>>(hW, es, en, cursor, dis, b1, out + 128, N);
}

// Round 3
// 532.872 us; speedup vs baseline: 5.4733x; 1.1410x over previous
//
#include <hip/hip_runtime.h>

// ---------------------------------------------------------------------------
// GCN encoder, 2 layers, N=100000 D=H=128, E=1.6M.
// Round 3: packed 64-bit histogram atomic (count<<32 | fixed24 weight-sum),
//          4 edges/thread for MLP, int2-packed CSR edge records.
// ws layout (4B words):
//   degcnt[2N] (u64) | dis[N] | cursor[N] | ep[2E] (int2) | hW[128N] | sums[512]
// ---------------------------------------------------------------------------

typedef unsigned long long u64;

__global__ __launch_bounds__(256) void k_init(u64* degcnt, int n) {
    int i = blockIdx.x * 256 + threadIdx.x;
    if (i < n) degcnt[i] = (u64)(1u << 24);   // deg = 1.0 (self-loop), count = 0
}

// one packed atomic per edge: +1 count (hi32), +w*2^24 (lo32)
__global__ __launch_bounds__(256) void k_hist(u64* degcnt,
                                              const float* __restrict__ w,
                                              const int* __restrict__ dst, int e) {
    int i0 = blockIdx.x * 1024 + threadIdx.x;
#pragma unroll
    for (int u = 0; u < 4; ++u) {
        int i = i0 + u * 256;
        if (i < e) {
            unsigned fx = (unsigned)(w[i] * 16777216.0f + 0.5f);
            atomicAdd(&degcnt[dst[i]], ((u64)1 << 32) | (u64)fx);
        }
    }
}

// dis = rsqrt(deg); cursor = count
__global__ __launch_bounds__(256) void k_dis(const u64* __restrict__ degcnt,
                                             float* dis, int* cursor, int n) {
    int i = blockIdx.x * 256 + threadIdx.x;
    if (i < n) {
        u64 v = degcnt[i];
        float deg = (float)(unsigned)(v & 0xffffffffull) * (1.0f / 16777216.0f);
        dis[i] = rsqrtf(deg);
        cursor[i] = (int)(v >> 32);
    }
}

// ---- exclusive scan over cursor[N] ----
__global__ __launch_bounds__(256) void k_scan1(int* data, int* sums, int n) {
    __shared__ int tmp[256];
    int gid = blockIdx.x * 256 + threadIdx.x;
    int v = (gid < n) ? data[gid] : 0;
    tmp[threadIdx.x] = v;
    __syncthreads();
    for (int off = 1; off < 256; off <<= 1) {
        int t = (threadIdx.x >= off) ? tmp[threadIdx.x - off] : 0;
        __syncthreads();
        tmp[threadIdx.x] += t;
        __syncthreads();
    }
    if (gid < n) data[gid] = tmp[threadIdx.x] - v;
    if (threadIdx.x == 255) sums[blockIdx.x] = tmp[255];
}

__global__ __launch_bounds__(512) void k_scan2(int* sums, int nb) {
    __shared__ int tmp[512];
    int v = (threadIdx.x < nb) ? sums[threadIdx.x] : 0;
    tmp[threadIdx.x] = v;
    __syncthreads();
    for (int off = 1; off < 512; off <<= 1) {
        int t = (threadIdx.x >= off) ? tmp[threadIdx.x - off] : 0;
        __syncthreads();
        tmp[threadIdx.x] += t;
        __syncthreads();
    }
    if (threadIdx.x < nb) sums[threadIdx.x] = tmp[threadIdx.x] - v;
}

__global__ __launch_bounds__(256) void k_scan3(int* data, const int* sums, int n) {
    int gid = blockIdx.x * 256 + threadIdx.x;
    if (gid < n) data[gid] += sums[blockIdx.x];
}

// scatter packed (src, norm) records into dst-buckets
__global__ __launch_bounds__(256) void k_scatter(const int* __restrict__ src,
                                                 const int* __restrict__ dst,
                                                 const float* __restrict__ ew,
                                                 const float* __restrict__ dis,
                                                 int* cursor, int2* ep, int e) {
    int i0 = blockIdx.x * 1024 + threadIdx.x;
#pragma unroll
    for (int u = 0; u < 4; ++u) {
        int i = i0 + u * 256;
        if (i < e) {
            int s = src[i], d = dst[i];
            float nm = dis[s] * ew[i] * dis[d];
            int pos = atomicAdd(&cursor[d], 1);
            ep[pos] = make_int2(s, __float_as_int(nm));
        }
    }
}

// C[row, 0..127] = A[row, 0..127] @ W[128,128].
__global__ __launch_bounds__(256) void k_gemm(const float* __restrict__ A, int lda,
                                              const float* __restrict__ W,
                                              float* __restrict__ C, int ldc, int n) {
    __shared__ float As[64][68];
    __shared__ float Ws[64][128];

    const int t = threadIdx.x;
    const int ty = t >> 4;
    const int tx = t & 15;
    const int row0 = blockIdx.x * 64;

    float acc[4][8];
#pragma unroll
    for (int i = 0; i < 4; i++)
#pragma unroll
        for (int j = 0; j < 8; j++) acc[i][j] = 0.f;

    for (int kc = 0; kc < 128; kc += 64) {
        {
            const int lr = t >> 2, q = t & 3;
            const int gr = row0 + lr;
            float4 v0, v1, v2, v3;
            if (gr < n) {
                const float4* ap = (const float4*)(A + (size_t)gr * lda + kc + q * 16);
                v0 = ap[0]; v1 = ap[1]; v2 = ap[2]; v3 = ap[3];
            } else {
                v0 = v1 = v2 = v3 = make_float4(0.f, 0.f, 0.f, 0.f);
            }
            float4* asp = (float4*)&As[lr][q * 16];
            asp[0] = v0; asp[1] = v1; asp[2] = v2; asp[3] = v3;
        }
        {
            const int wr = t >> 2, q = t & 3;
            const float4* wp = (const float4*)(W + (size_t)(kc + wr) * 128 + q * 32);
            float4* wd = (float4*)&Ws[wr][q * 32];
#pragma unroll
            for (int u = 0; u < 8; u++) wd[u] = wp[u];
        }
        __syncthreads();

#pragma unroll 8
        for (int k = 0; k < 64; k++) {
            float a[4];
#pragma unroll
            for (int i = 0; i < 4; i++) a[i] = As[ty * 4 + i][k];
            float4 w0 = *(const float4*)&Ws[k][tx * 8];
            float4 w1 = *(const float4*)&Ws[k][tx * 8 + 4];
            float w[8] = {w0.x, w0.y, w0.z, w0.w, w1.x, w1.y, w1.z, w1.w};
#pragma unroll
            for (int i = 0; i < 4; i++)
#pragma unroll
                for (int j = 0; j < 8; j++) acc[i][j] += a[i] * w[j];
        }
        __syncthreads();
    }

#pragma unroll
    for (int i = 0; i < 4; i++) {
        int gr = row0 + ty * 4 + i;
        if (gr < n) {
            float4* cp = (float4*)(C + (size_t)gr * ldc + tx * 8);
            cp[0] = make_float4(acc[i][0], acc[i][1], acc[i][2], acc[i][3]);
            cp[1] = make_float4(acc[i][4], acc[i][5], acc[i][6], acc[i][7]);
        }
    }
}

// fused: out[d, c] = relu( dis[d]^2 * hW[d,c] + sum_j norm_j * hW[src_j, c] + b[c] )
// one wave per dst node; lane handles features {2*lane, 2*lane+1}.
__global__ __launch_bounds__(256) void k_agg(const float* __restrict__ hW,
                                             const int2* __restrict__ ep,
                                             const int* __restrict__ endptr,
                                             const float* __restrict__ dis,
                                             const float* __restrict__ bias,
                                             float* __restrict__ outcol,  // stride 256
                                             int n) {
    int wid = blockIdx.x * 4 + (threadIdx.x >> 6);
    int lane = threadIdx.x & 63;
    if (wid >= n) return;

    int end   = endptr[wid];
    int start = (wid == 0) ? 0 : endptr[wid - 1];
    start = __builtin_amdgcn_readfirstlane(start);
    end   = __builtin_amdgcn_readfirstlane(end);

    float di = dis[wid];
    float2 h = *(const float2*)(hW + (size_t)wid * 128 + lane * 2);
    float2 acc;
    acc.x = di * di * h.x;
    acc.y = di * di * h.y;

    for (int j = start; j < end; ++j) {
        int2 rec = ep[j];
        float nm = __int_as_float(rec.y);
        float2 v = *(const float2*)(hW + (size_t)rec.x * 128 + lane * 2);
        acc.x += nm * v.x;
        acc.y += nm * v.y;
    }

    float2 b = *(const float2*)(bias + lane * 2);
    float2 o;
    o.x = fmaxf(acc.x + b.x, 0.f);
    o.y = fmaxf(acc.y + b.y, 0.f);
    *(float2*)(outcol + (size_t)wid * 256 + lane * 2) = o;
}

extern "C" void kernel_launch(void* const* d_in, const int* in_sizes, int n_in,
                              void* d_out, int out_size, void* d_ws, size_t ws_size,
                              hipStream_t stream) {
    const float* x  = (const float*)d_in[0];
    const float* ew = (const float*)d_in[1];
    const float* W0 = (const float*)d_in[2];
    const float* b0 = (const float*)d_in[3];
    const float* W1 = (const float*)d_in[4];
    const float* b1 = (const float*)d_in[5];
    const int*   ei = (const int*)d_in[6];

    const int N = in_sizes[0] / 128;
    const int E = in_sizes[1];
    const int* src = ei;
    const int* dst = ei + E;
    float* out = (float*)d_out;   // [N, 256]

    // ws layout (4B words), degcnt first for 8B alignment
    u64*   degcnt = (u64*)d_ws;
    float* dis    = (float*)(degcnt + N);
    int*   cursor = (int*)(dis + N);
    int2*  ep     = (int2*)(cursor + N);
    float* hW     = (float*)(ep + E);
    int*   sums   = (int*)(hW + (size_t)N * 128);

    const int gN = (N + 255) / 256;
    const int gE4 = (E + 1023) / 1024;
    const int gG = (N + 63) / 64;
    const int gA = (N + 3) / 4;
    const int nb = gN;

    // ---- CSR build + normalization ----
    k_init<<<gN, 256, 0, stream>>>(degcnt, N);
    k_hist<<<gE4, 256, 0, stream>>>(degcnt, ew, dst, E);
    k_dis<<<gN, 256, 0, stream>>>(degcnt, dis, cursor, N);
    k_scan1<<<nb, 256, 0, stream>>>(cursor, sums, N);
    k_scan2<<<1, 512, 0, stream>>>(sums, nb);
    k_scan3<<<nb, 256, 0, stream>>>(cursor, sums, N);
    k_scatter<<<gE4, 256, 0, stream>>>(src, dst, ew, dis, cursor, ep, E);
    // cursor now holds row END pointers.

    // ---- layer 1 ----
    k_gemm<<<gG, 256, 0, stream>>>(x, 128, W0, hW, 128, N);
    k_agg<<<gA, 256, 0, stream>>>(hW, ep, cursor, dis, b0, out, N);

    // ---- layer 2 ----
    k_gemm<<<gG, 256, 0, stream>>>(out, 256, W1, hW, 128, N);
    k_agg<<<gA, 256, 0, stream>>>(hW, ep, cursor, dis, b1, out + 128, N);
}

// Round 4
// 406.998 us; speedup vs baseline: 7.1661x; 1.3093x over previous
//
#include <hip/hip_runtime.h>
#include <hip/hip_fp16.h>

// ---------------------------------------------------------------------------
// GCN encoder, 2 layers, N=100000 D=H=128, E=1.6M.
// Round 4: hW stored fp16 (halves gather traffic in k_agg), edge loop
//          unrolled x4 with independent in-flight gathers.
// ws layout (4B words):
//   degcnt[2N] (u64) | dis[N] | cursor[N] | ep[2E] (int2) | hW[64N] (half) | sums[512]
// ---------------------------------------------------------------------------

typedef unsigned long long u64;

__global__ __launch_bounds__(256) void k_init(u64* degcnt, int n) {
    int i = blockIdx.x * 256 + threadIdx.x;
    if (i < n) degcnt[i] = (u64)(1u << 24);   // deg = 1.0 (self-loop), count = 0
}

// one packed atomic per edge: +1 count (hi32), +w*2^24 (lo32)
__global__ __launch_bounds__(256) void k_hist(u64* degcnt,
                                              const float* __restrict__ w,
                                              const int* __restrict__ dst, int e) {
    int i0 = blockIdx.x * 1024 + threadIdx.x;
#pragma unroll
    for (int u = 0; u < 4; ++u) {
        int i = i0 + u * 256;
        if (i < e) {
            unsigned fx = (unsigned)(w[i] * 16777216.0f + 0.5f);
            atomicAdd(&degcnt[dst[i]], ((u64)1 << 32) | (u64)fx);
        }
    }
}

// dis = rsqrt(deg); cursor = count
__global__ __launch_bounds__(256) void k_dis(const u64* __restrict__ degcnt,
                                             float* dis, int* cursor, int n) {
    int i = blockIdx.x * 256 + threadIdx.x;
    if (i < n) {
        u64 v = degcnt[i];
        float deg = (float)(unsigned)(v & 0xffffffffull) * (1.0f / 16777216.0f);
        dis[i] = rsqrtf(deg);
        cursor[i] = (int)(v >> 32);
    }
}

// ---- exclusive scan over cursor[N] ----
__global__ __launch_bounds__(256) void k_scan1(int* data, int* sums, int n) {
    __shared__ int tmp[256];
    int gid = blockIdx.x * 256 + threadIdx.x;
    int v = (gid < n) ? data[gid] : 0;
    tmp[threadIdx.x] = v;
    __syncthreads();
    for (int off = 1; off < 256; off <<= 1) {
        int t = (threadIdx.x >= off) ? tmp[threadIdx.x - off] : 0;
        __syncthreads();
        tmp[threadIdx.x] += t;
        __syncthreads();
    }
    if (gid < n) data[gid] = tmp[threadIdx.x] - v;
    if (threadIdx.x == 255) sums[blockIdx.x] = tmp[255];
}

__global__ __launch_bounds__(512) void k_scan2(int* sums, int nb) {
    __shared__ int tmp[512];
    int v = (threadIdx.x < nb) ? sums[threadIdx.x] : 0;
    tmp[threadIdx.x] = v;
    __syncthreads();
    for (int off = 1; off < 512; off <<= 1) {
        int t = (threadIdx.x >= off) ? tmp[threadIdx.x - off] : 0;
        __syncthreads();
        tmp[threadIdx.x] += t;
        __syncthreads();
    }
    if (threadIdx.x < nb) sums[threadIdx.x] = tmp[threadIdx.x] - v;
}

__global__ __launch_bounds__(256) void k_scan3(int* data, const int* sums, int n) {
    int gid = blockIdx.x * 256 + threadIdx.x;
    if (gid < n) data[gid] += sums[blockIdx.x];
}

// scatter packed (src, norm) records into dst-buckets
__global__ __launch_bounds__(256) void k_scatter(const int* __restrict__ src,
                                                 const int* __restrict__ dst,
                                                 const float* __restrict__ ew,
                                                 const float* __restrict__ dis,
                                                 int* cursor, int2* ep, int e) {
    int i0 = blockIdx.x * 1024 + threadIdx.x;
#pragma unroll
    for (int u = 0; u < 4; ++u) {
        int i = i0 + u * 256;
        if (i < e) {
            int s = src[i], d = dst[i];
            float nm = dis[s] * ew[i] * dis[d];
            int pos = atomicAdd(&cursor[d], 1);
            ep[pos] = make_int2(s, __float_as_int(nm));
        }
    }
}

// C[row, 0..127] (fp16) = A[row, 0..127] (fp32) @ W[128,128] (fp32)
__global__ __launch_bounds__(256) void k_gemm(const float* __restrict__ A, int lda,
                                              const float* __restrict__ W,
                                              __half* __restrict__ C, int n) {
    __shared__ float As[64][68];
    __shared__ float Ws[64][128];

    const int t = threadIdx.x;
    const int ty = t >> 4;
    const int tx = t & 15;
    const int row0 = blockIdx.x * 64;

    float acc[4][8];
#pragma unroll
    for (int i = 0; i < 4; i++)
#pragma unroll
        for (int j = 0; j < 8; j++) acc[i][j] = 0.f;

    for (int kc = 0; kc < 128; kc += 64) {
        {
            const int lr = t >> 2, q = t & 3;
            const int gr = row0 + lr;
            float4 v0, v1, v2, v3;
            if (gr < n) {
                const float4* ap = (const float4*)(A + (size_t)gr * lda + kc + q * 16);
                v0 = ap[0]; v1 = ap[1]; v2 = ap[2]; v3 = ap[3];
            } else {
                v0 = v1 = v2 = v3 = make_float4(0.f, 0.f, 0.f, 0.f);
            }
            float4* asp = (float4*)&As[lr][q * 16];
            asp[0] = v0; asp[1] = v1; asp[2] = v2; asp[3] = v3;
        }
        {
            const int wr = t >> 2, q = t & 3;
            const float4* wp = (const float4*)(W + (size_t)(kc + wr) * 128 + q * 32);
            float4* wd = (float4*)&Ws[wr][q * 32];
#pragma unroll
            for (int u = 0; u < 8; u++) wd[u] = wp[u];
        }
        __syncthreads();

#pragma unroll 8
        for (int k = 0; k < 64; k++) {
            float a[4];
#pragma unroll
            for (int i = 0; i < 4; i++) a[i] = As[ty * 4 + i][k];
            float4 w0 = *(const float4*)&Ws[k][tx * 8];
            float4 w1 = *(const float4*)&Ws[k][tx * 8 + 4];
            float w[8] = {w0.x, w0.y, w0.z, w0.w, w1.x, w1.y, w1.z, w1.w};
#pragma unroll
            for (int i = 0; i < 4; i++)
#pragma unroll
                for (int j = 0; j < 8; j++) acc[i][j] += a[i] * w[j];
        }
        __syncthreads();
    }

#pragma unroll
    for (int i = 0; i < 4; i++) {
        int gr = row0 + ty * 4 + i;
        if (gr < n) {
            union { int4 i4; __half h[8]; } pk;
#pragma unroll
            for (int j = 0; j < 8; j++) pk.h[j] = __float2half(acc[i][j]);
            *(int4*)(C + (size_t)gr * 128 + tx * 8) = pk.i4;
        }
    }
}

// fused: out[d, c] = relu( dis[d]^2 * hW[d,c] + sum_j norm_j * hW[src_j, c] + b[c] )
// one wave per dst node; lane handles features {2*lane, 2*lane+1}; x4 unroll.
__global__ __launch_bounds__(256) void k_agg(const __half* __restrict__ hW,
                                             const int2* __restrict__ ep,
                                             const int* __restrict__ endptr,
                                             const float* __restrict__ dis,
                                             const float* __restrict__ bias,
                                             float* __restrict__ outcol,  // stride 256
                                             int n) {
    int wid = blockIdx.x * 4 + (threadIdx.x >> 6);
    int lane = threadIdx.x & 63;
    if (wid >= n) return;

    int end   = endptr[wid];
    int start = (wid == 0) ? 0 : endptr[wid - 1];
    start = __builtin_amdgcn_readfirstlane(start);
    end   = __builtin_amdgcn_readfirstlane(end);

    float di = dis[wid];
    float2 h = __half22float2(*(const __half2*)(hW + (size_t)wid * 128 + lane * 2));
    float2 acc;
    acc.x = di * di * h.x;
    acc.y = di * di * h.y;

    int j = start;
    for (; j + 3 < end; j += 4) {
        int2 r0 = ep[j];
        int2 r1 = ep[j + 1];
        int2 r2 = ep[j + 2];
        int2 r3 = ep[j + 3];
        __half2 v0 = *(const __half2*)(hW + (size_t)r0.x * 128 + lane * 2);
        __half2 v1 = *(const __half2*)(hW + (size_t)r1.x * 128 + lane * 2);
        __half2 v2 = *(const __half2*)(hW + (size_t)r2.x * 128 + lane * 2);
        __half2 v3 = *(const __half2*)(hW + (size_t)r3.x * 128 + lane * 2);
        float n0 = __int_as_float(r0.y), n1 = __int_as_float(r1.y);
        float n2 = __int_as_float(r2.y), n3 = __int_as_float(r3.y);
        float2 f0 = __half22float2(v0), f1 = __half22float2(v1);
        float2 f2 = __half22float2(v2), f3 = __half22float2(v3);
        acc.x += n0 * f0.x + n1 * f1.x + n2 * f2.x + n3 * f3.x;
        acc.y += n0 * f0.y + n1 * f1.y + n2 * f2.y + n3 * f3.y;
    }
    for (; j < end; ++j) {
        int2 rec = ep[j];
        float nm = __int_as_float(rec.y);
        float2 v = __half22float2(*(const __half2*)(hW + (size_t)rec.x * 128 + lane * 2));
        acc.x += nm * v.x;
        acc.y += nm * v.y;
    }

    float2 b = *(const float2*)(bias + lane * 2);
    float2 o;
    o.x = fmaxf(acc.x + b.x, 0.f);
    o.y = fmaxf(acc.y + b.y, 0.f);
    *(float2*)(outcol + (size_t)wid * 256 + lane * 2) = o;
}

extern "C" void kernel_launch(void* const* d_in, const int* in_sizes, int n_in,
                              void* d_out, int out_size, void* d_ws, size_t ws_size,
                              hipStream_t stream) {
    const float* x  = (const float*)d_in[0];
    const float* ew = (const float*)d_in[1];
    const float* W0 = (const float*)d_in[2];
    const float* b0 = (const float*)d_in[3];
    const float* W1 = (const float*)d_in[4];
    const float* b1 = (const float*)d_in[5];
    const int*   ei = (const int*)d_in[6];

    const int N = in_sizes[0] / 128;
    const int E = in_sizes[1];
    const int* src = ei;
    const int* dst = ei + E;
    float* out = (float*)d_out;   // [N, 256]

    // ws layout (4B words), degcnt first for 8B alignment
    u64*   degcnt = (u64*)d_ws;
    float* dis    = (float*)(degcnt + N);
    int*   cursor = (int*)(dis + N);
    int2*  ep     = (int2*)(cursor + N);
    __half* hW    = (__half*)(ep + E);
    int*   sums   = (int*)((float*)hW + (size_t)N * 64);  // N*128 halves = N*64 floats

    const int gN = (N + 255) / 256;
    const int gE4 = (E + 1023) / 1024;
    const int gG = (N + 63) / 64;
    const int gA = (N + 3) / 4;
    const int nb = gN;

    // ---- CSR build + normalization ----
    k_init<<<gN, 256, 0, stream>>>(degcnt, N);
    k_hist<<<gE4, 256, 0, stream>>>(degcnt, ew, dst, E);
    k_dis<<<gN, 256, 0, stream>>>(degcnt, dis, cursor, N);
    k_scan1<<<nb, 256, 0, stream>>>(cursor, sums, N);
    k_scan2<<<1, 512, 0, stream>>>(sums, nb);
    k_scan3<<<nb, 256, 0, stream>>>(cursor, sums, N);
    k_scatter<<<gE4, 256, 0, stream>>>(src, dst, ew, dis, cursor, ep, E);
    // cursor now holds row END pointers.

    // ---- layer 1 ----
    k_gemm<<<gG, 256, 0, stream>>>(x, 128, W0, hW, N);
    k_agg<<<gA, 256, 0, stream>>>(hW, ep, cursor, dis, b0, out, N);

    // ---- layer 2 ----
    k_gemm<<<gG, 256, 0, stream>>>(out, 256, W1, hW, N);
    k_agg<<<gA, 256, 0, stream>>>(hW, ep, cursor, dis, b1, out + 128, N);
}

// Round 5
// 368.206 us; speedup vs baseline: 7.9211x; 1.1054x over previous
//
#include <hip/hip_runtime.h>
#include <hip/hip_fp16.h>

// ---------------------------------------------------------------------------
// GCN encoder, 2 layers, N=100000 D=H=128, E=1.6M.
// Round 5: rank-from-histogram-atomic -> atomic-free scatter; unroll-8 in
//          hist (atomic MLP) and agg (gather MLP). hW stays fp16.
// ws layout (4B words):
//   degcnt[2N] (u64) | dis[N] | cursor[N] | ep[2E] (int2) | hW[64N] (half)
//   | rank[E/2] (u16) | sums[512]
// ---------------------------------------------------------------------------

typedef unsigned long long u64;

__global__ __launch_bounds__(256) void k_init(u64* degcnt, int n) {
    int i = blockIdx.x * 256 + threadIdx.x;
    if (i < n) degcnt[i] = (u64)(1u << 24);   // deg = 1.0 (self-loop), count = 0
}

// one packed atomic per edge: +1 count (hi32), +w*2^24 (lo32).
// atomic return gives this edge's unique rank within its dst bucket.
__global__ __launch_bounds__(256) void k_hist(u64* degcnt,
                                              const float* __restrict__ w,
                                              const int* __restrict__ dst,
                                              unsigned short* __restrict__ rank, int e) {
    int i0 = blockIdx.x * 2048 + threadIdx.x;
#pragma unroll
    for (int u = 0; u < 8; ++u) {
        int i = i0 + u * 256;
        if (i < e) {
            unsigned fx = (unsigned)(w[i] * 16777216.0f + 0.5f);
            u64 old = atomicAdd(&degcnt[dst[i]], ((u64)1 << 32) | (u64)fx);
            rank[i] = (unsigned short)(old >> 32);
        }
    }
}

// dis = rsqrt(deg); cursor = count
__global__ __launch_bounds__(256) void k_dis(const u64* __restrict__ degcnt,
                                             float* dis, int* cursor, int n) {
    int i = blockIdx.x * 256 + threadIdx.x;
    if (i < n) {
        u64 v = degcnt[i];
        float deg = (float)(unsigned)(v & 0xffffffffull) * (1.0f / 16777216.0f);
        dis[i] = rsqrtf(deg);
        cursor[i] = (int)(v >> 32);
    }
}

// ---- exclusive scan over cursor[N] ----
__global__ __launch_bounds__(256) void k_scan1(int* data, int* sums, int n) {
    __shared__ int tmp[256];
    int gid = blockIdx.x * 256 + threadIdx.x;
    int v = (gid < n) ? data[gid] : 0;
    tmp[threadIdx.x] = v;
    __syncthreads();
    for (int off = 1; off < 256; off <<= 1) {
        int t = (threadIdx.x >= off) ? tmp[threadIdx.x - off] : 0;
        __syncthreads();
        tmp[threadIdx.x] += t;
        __syncthreads();
    }
    if (gid < n) data[gid] = tmp[threadIdx.x] - v;
    if (threadIdx.x == 255) sums[blockIdx.x] = tmp[255];
}

__global__ __launch_bounds__(512) void k_scan2(int* sums, int nb) {
    __shared__ int tmp[512];
    int v = (threadIdx.x < nb) ? sums[threadIdx.x] : 0;
    tmp[threadIdx.x] = v;
    __syncthreads();
    for (int off = 1; off < 512; off <<= 1) {
        int t = (threadIdx.x >= off) ? tmp[threadIdx.x - off] : 0;
        __syncthreads();
        tmp[threadIdx.x] += t;
        __syncthreads();
    }
    if (threadIdx.x < nb) sums[threadIdx.x] = tmp[threadIdx.x] - v;
}

__global__ __launch_bounds__(256) void k_scan3(int* data, const int* sums, int n) {
    int gid = blockIdx.x * 256 + threadIdx.x;
    if (gid < n) data[gid] += sums[blockIdx.x];
}

// atomic-free scatter: pos = rowstart[dst] + rank
__global__ __launch_bounds__(256) void k_scatter(const int* __restrict__ src,
                                                 const int* __restrict__ dst,
                                                 const float* __restrict__ ew,
                                                 const unsigned short* __restrict__ rank,
                                                 const float* __restrict__ dis,
                                                 const int* __restrict__ rowstart,
                                                 int2* ep, int e) {
    int i0 = blockIdx.x * 2048 + threadIdx.x;
#pragma unroll
    for (int u = 0; u < 8; ++u) {
        int i = i0 + u * 256;
        if (i < e) {
            int s = src[i], d = dst[i];
            float nm = dis[s] * ew[i] * dis[d];
            int pos = rowstart[d] + (int)rank[i];
            ep[pos] = make_int2(s, __float_as_int(nm));
        }
    }
}

// C[row, 0..127] (fp16) = A[row, 0..127] (fp32) @ W[128,128] (fp32)
__global__ __launch_bounds__(256) void k_gemm(const float* __restrict__ A, int lda,
                                              const float* __restrict__ W,
                                              __half* __restrict__ C, int n) {
    __shared__ float As[64][68];
    __shared__ float Ws[64][128];

    const int t = threadIdx.x;
    const int ty = t >> 4;
    const int tx = t & 15;
    const int row0 = blockIdx.x * 64;

    float acc[4][8];
#pragma unroll
    for (int i = 0; i < 4; i++)
#pragma unroll
        for (int j = 0; j < 8; j++) acc[i][j] = 0.f;

    for (int kc = 0; kc < 128; kc += 64) {
        {
            const int lr = t >> 2, q = t & 3;
            const int gr = row0 + lr;
            float4 v0, v1, v2, v3;
            if (gr < n) {
                const float4* ap = (const float4*)(A + (size_t)gr * lda + kc + q * 16);
                v0 = ap[0]; v1 = ap[1]; v2 = ap[2]; v3 = ap[3];
            } else {
                v0 = v1 = v2 = v3 = make_float4(0.f, 0.f, 0.f, 0.f);
            }
            float4* asp = (float4*)&As[lr][q * 16];
            asp[0] = v0; asp[1] = v1; asp[2] = v2; asp[3] = v3;
        }
        {
            const int wr = t >> 2, q = t & 3;
            const float4* wp = (const float4*)(W + (size_t)(kc + wr) * 128 + q * 32);
            float4* wd = (float4*)&Ws[wr][q * 32];
#pragma unroll
            for (int u = 0; u < 8; u++) wd[u] = wp[u];
        }
        __syncthreads();

#pragma unroll 8
        for (int k = 0; k < 64; k++) {
            float a[4];
#pragma unroll
            for (int i = 0; i < 4; i++) a[i] = As[ty * 4 + i][k];
            float4 w0 = *(const float4*)&Ws[k][tx * 8];
            float4 w1 = *(const float4*)&Ws[k][tx * 8 + 4];
            float w[8] = {w0.x, w0.y, w0.z, w0.w, w1.x, w1.y, w1.z, w1.w};
#pragma unroll
            for (int i = 0; i < 4; i++)
#pragma unroll
                for (int j = 0; j < 8; j++) acc[i][j] += a[i] * w[j];
        }
        __syncthreads();
    }

#pragma unroll
    for (int i = 0; i < 4; i++) {
        int gr = row0 + ty * 4 + i;
        if (gr < n) {
            union { int4 i4; __half h[8]; } pk;
#pragma unroll
            for (int j = 0; j < 8; j++) pk.h[j] = __float2half(acc[i][j]);
            *(int4*)(C + (size_t)gr * 128 + tx * 8) = pk.i4;
        }
    }
}

// fused: out[d, c] = relu( dis[d]^2 * hW[d,c] + sum_j norm_j * hW[src_j, c] + b[c] )
// one wave per dst node; lane handles features {2*lane, 2*lane+1}; x8 unroll.
__global__ __launch_bounds__(256) void k_agg(const __half* __restrict__ hW,
                                             const int2* __restrict__ ep,
                                             const int* __restrict__ rowstart,
                                             const float* __restrict__ dis,
                                             const float* __restrict__ bias,
                                             float* __restrict__ outcol,  // stride 256
                                             int n, int e) {
    int wid = blockIdx.x * 4 + (threadIdx.x >> 6);
    int lane = threadIdx.x & 63;
    if (wid >= n) return;

    int start = rowstart[wid];
    int end   = (wid == n - 1) ? e : rowstart[wid + 1];
    start = __builtin_amdgcn_readfirstlane(start);
    end   = __builtin_amdgcn_readfirstlane(end);

    float di = dis[wid];
    float2 h = __half22float2(*(const __half2*)(hW + (size_t)wid * 128 + lane * 2));
    float2 acc;
    acc.x = di * di * h.x;
    acc.y = di * di * h.y;

    int j = start;
    for (; j + 7 < end; j += 8) {
        int2 r[8];
        __half2 v[8];
#pragma unroll
        for (int u = 0; u < 8; ++u) r[u] = ep[j + u];
#pragma unroll
        for (int u = 0; u < 8; ++u)
            v[u] = *(const __half2*)(hW + (size_t)r[u].x * 128 + lane * 2);
#pragma unroll
        for (int u = 0; u < 8; ++u) {
            float nm = __int_as_float(r[u].y);
            float2 f = __half22float2(v[u]);
            acc.x += nm * f.x;
            acc.y += nm * f.y;
        }
    }
    for (; j < end; ++j) {
        int2 rec = ep[j];
        float nm = __int_as_float(rec.y);
        float2 v = __half22float2(*(const __half2*)(hW + (size_t)rec.x * 128 + lane * 2));
        acc.x += nm * v.x;
        acc.y += nm * v.y;
    }

    float2 b = *(const float2*)(bias + lane * 2);
    float2 o;
    o.x = fmaxf(acc.x + b.x, 0.f);
    o.y = fmaxf(acc.y + b.y, 0.f);
    *(float2*)(outcol + (size_t)wid * 256 + lane * 2) = o;
}

extern "C" void kernel_launch(void* const* d_in, const int* in_sizes, int n_in,
                              void* d_out, int out_size, void* d_ws, size_t ws_size,
                              hipStream_t stream) {
    const float* x  = (const float*)d_in[0];
    const float* ew = (const float*)d_in[1];
    const float* W0 = (const float*)d_in[2];
    const float* b0 = (const float*)d_in[3];
    const float* W1 = (const float*)d_in[4];
    const float* b1 = (const float*)d_in[5];
    const int*   ei = (const int*)d_in[6];

    const int N = in_sizes[0] / 128;
    const int E = in_sizes[1];
    const int* src = ei;
    const int* dst = ei + E;
    float* out = (float*)d_out;   // [N, 256]

    // ws layout (4B words), degcnt first for 8B alignment
    u64*   degcnt = (u64*)d_ws;
    float* dis    = (float*)(degcnt + N);
    int*   cursor = (int*)(dis + N);
    int2*  ep     = (int2*)(cursor + N);
    __half* hW    = (__half*)(ep + E);
    unsigned short* rank = (unsigned short*)((float*)hW + (size_t)N * 64);
    int*   sums   = (int*)((float*)hW + (size_t)N * 64 + (size_t)(E + 1) / 2);

    const int gN = (N + 255) / 256;
    const int gE8 = (E + 2047) / 2048;
    const int gG = (N + 63) / 64;
    const int gA = (N + 3) / 4;
    const int nb = gN;

    // ---- CSR build + normalization ----
    k_init<<<gN, 256, 0, stream>>>(degcnt, N);
    k_hist<<<gE8, 256, 0, stream>>>(degcnt, ew, dst, rank, E);
    k_dis<<<gN, 256, 0, stream>>>(degcnt, dis, cursor, N);
    k_scan1<<<nb, 256, 0, stream>>>(cursor, sums, N);
    k_scan2<<<1, 512, 0, stream>>>(sums, nb);
    k_scan3<<<nb, 256, 0, stream>>>(cursor, sums, N);
    k_scatter<<<gE8, 256, 0, stream>>>(src, dst, ew, rank, dis, cursor, ep, E);
    // cursor holds row START pointers (unchanged by scatter).

    // ---- layer 1 ----
    k_gemm<<<gG, 256, 0, stream>>>(x, 128, W0, hW, N);
    k_agg<<<gA, 256, 0, stream>>>(hW, ep, cursor, dis, b0, out, N, E);

    // ---- layer 2 ----
    k_gemm<<<gG, 256, 0, stream>>>(out, 256, W1, hW, N);
    k_agg<<<gA, 256, 0, stream>>>(hW, ep, cursor, dis, b1, out + 128, N, E);
}

// Round 6
// 298.711 us; speedup vs baseline: 9.7639x; 1.2327x over previous
//
#include <hip/hip_runtime.h>
#include <hip/hip_fp16.h>

// ---------------------------------------------------------------------------
// GCN encoder, 2 layers, N=100000 D=H=128, E=1.6M.
// Round 6: (a) hist+gemm1 fused into one heterogeneous dispatch (gemm hides
//          under the atomic-bound hist); (b) MFMA f16 GEMM (16x16x32_f16,
//          fragment-order W precomputed once, A staged fp32->f16 in LDS).
// ws layout (4B words):
//   degcnt[2N] (u64) | dis[N] | cursor[N] | ep[2E] (int2) | hW[64N] (half)
//   | rank[E/2] (u16) | Wf[2*16384 halves] | sums[512]
// ---------------------------------------------------------------------------

typedef unsigned long long u64;
typedef _Float16 f16;
typedef f16 f16x4 __attribute__((ext_vector_type(4)));
typedef f16 f16x8 __attribute__((ext_vector_type(8)));
typedef float f32x4 __attribute__((ext_vector_type(4)));

__global__ __launch_bounds__(256) void k_init(u64* degcnt, int n) {
    int i = blockIdx.x * 256 + threadIdx.x;
    if (i < n) degcnt[i] = (u64)(1u << 24);   // deg = 1.0 (self-loop), count = 0
}

// Pack W0,W1 (fp32 [128][128]) into MFMA fragment order:
// Wf[sel][ks*8+nt][lane][j] = W[k(lane,j)][nt*16 + (lane&15)]
//   k(lane,j) = ks*32 + ((lane>>4)&3)*4 + (j&3) + 16*(j>>2)
__global__ __launch_bounds__(256) void k_wfrag(const float* __restrict__ W0,
                                               const float* __restrict__ W1,
                                               __half* __restrict__ Wf) {
    int idx = blockIdx.x * 256 + threadIdx.x;     // 0..4095
    const float* W = (idx < 2048) ? W0 : W1;
    int id = idx & 2047;
    int l = id & 63, nt = (id >> 6) & 7, ks = id >> 9;
    int n = nt * 16 + (l & 15);
    int kb = ks * 32 + ((l >> 4) & 3) * 4;
    union { int4 v; __half h[8]; } pk;
#pragma unroll
    for (int j = 0; j < 8; ++j) {
        int k = kb + (j & 3) + 16 * (j >> 2);
        pk.h[j] = __float2half(W[k * 128 + n]);
    }
    *(int4*)(Wf + (size_t)idx * 8) = pk.v;
}

// dis = rsqrt(deg); cursor = count
__global__ __launch_bounds__(256) void k_dis(const u64* __restrict__ degcnt,
                                             float* dis, int* cursor, int n) {
    int i = blockIdx.x * 256 + threadIdx.x;
    if (i < n) {
        u64 v = degcnt[i];
        float deg = (float)(unsigned)(v & 0xffffffffull) * (1.0f / 16777216.0f);
        dis[i] = rsqrtf(deg);
        cursor[i] = (int)(v >> 32);
    }
}

// ---- exclusive scan over cursor[N] ----
__global__ __launch_bounds__(256) void k_scan1(int* data, int* sums, int n) {
    __shared__ int tmp[256];
    int gid = blockIdx.x * 256 + threadIdx.x;
    int v = (gid < n) ? data[gid] : 0;
    tmp[threadIdx.x] = v;
    __syncthreads();
    for (int off = 1; off < 256; off <<= 1) {
        int t = (threadIdx.x >= off) ? tmp[threadIdx.x - off] : 0;
        __syncthreads();
        tmp[threadIdx.x] += t;
        __syncthreads();
    }
    if (gid < n) data[gid] = tmp[threadIdx.x] - v;
    if (threadIdx.x == 255) sums[blockIdx.x] = tmp[255];
}

__global__ __launch_bounds__(512) void k_scan2(int* sums, int nb) {
    __shared__ int tmp[512];
    int v = (threadIdx.x < nb) ? sums[threadIdx.x] : 0;
    tmp[threadIdx.x] = v;
    __syncthreads();
    for (int off = 1; off < 512; off <<= 1) {
        int t = (threadIdx.x >= off) ? tmp[threadIdx.x - off] : 0;
        __syncthreads();
        tmp[threadIdx.x] += t;
        __syncthreads();
    }
    if (threadIdx.x < nb) sums[threadIdx.x] = tmp[threadIdx.x] - v;
}

__global__ __launch_bounds__(256) void k_scan3(int* data, const int* sums, int n) {
    int gid = blockIdx.x * 256 + threadIdx.x;
    if (gid < n) data[gid] += sums[blockIdx.x];
}

// atomic-free scatter: pos = rowstart[dst] + rank
__global__ __launch_bounds__(256) void k_scatter(const int* __restrict__ src,
                                                 const int* __restrict__ dst,
                                                 const float* __restrict__ ew,
                                                 const unsigned short* __restrict__ rank,
                                                 const float* __restrict__ dis,
                                                 const int* __restrict__ rowstart,
                                                 int2* ep, int e) {
    int i0 = blockIdx.x * 2048 + threadIdx.x;
#pragma unroll
    for (int u = 0; u < 8; ++u) {
        int i = i0 + u * 256;
        if (i < e) {
            int s = src[i], d = dst[i];
            float nm = dis[s] * ew[i] * dis[d];
            int pos = rowstart[d] + (int)rank[i];
            ep[pos] = make_int2(s, __float_as_int(nm));
        }
    }
}

// ---- MFMA f16 GEMM body: C[64 rows x 128] (fp16) = A(fp32) @ W (via Wf) ----
// Block = 256 threads = 4 waves; wave w owns rows 16w..16w+15 of the tile.
__device__ __forceinline__ void gemm_body(const float* __restrict__ A, int lda,
                                          const __half* __restrict__ Wf,
                                          __half* __restrict__ C, int n,
                                          int bid, int t, f16* AF) {
    const int row0 = bid * 64;
    // stage A tile fp32 -> f16 fragment order:
    // AF[(w*4+ks)*64 + lane][8] ; lane = (r&15) + 16*s holds k = ks*32+4s+j+16g
    {
        const int r = t >> 2, q = t & 3;       // q = kstep this thread stages
        const int gr = row0 + r;
        float4 v[8];
        if (gr < n) {
            const float4* ap = (const float4*)(A + (size_t)gr * lda + q * 32);
#pragma unroll
            for (int u = 0; u < 8; ++u) v[u] = ap[u];
        } else {
#pragma unroll
            for (int u = 0; u < 8; ++u) v[u] = make_float4(0.f, 0.f, 0.f, 0.f);
        }
        const int w = r >> 4, rr = r & 15;
#pragma unroll
        for (int u = 0; u < 8; ++u) {
            const int s = u & 3, g = u >> 2;
            f16x4 hv;
            hv[0] = (f16)v[u].x; hv[1] = (f16)v[u].y;
            hv[2] = (f16)v[u].z; hv[3] = (f16)v[u].w;
            const int off = ((w * 4 + q) * 64 + rr + 16 * s) * 8 + g * 4;
            *(f16x4*)&AF[off] = hv;
        }
    }
    __syncthreads();

    const int w2 = t >> 6, l = t & 63;
    f32x4 acc[8];
#pragma unroll
    for (int i = 0; i < 8; ++i) acc[i] = (f32x4){0.f, 0.f, 0.f, 0.f};

#pragma unroll
    for (int ks = 0; ks < 4; ++ks) {
        f16x8 af = *(f16x8*)&AF[((w2 * 4 + ks) * 64 + l) * 8];
#pragma unroll
        for (int nt = 0; nt < 8; ++nt) {
            f16x8 wf = *(const f16x8*)(Wf + ((size_t)(ks * 8 + nt) * 64 + l) * 8);
            // D = (W^T-tile)(x^T-tile): D row = feature, D col = node
            acc[nt] = __builtin_amdgcn_mfma_f32_16x16x32_f16(wf, af, acc[nt], 0, 0, 0);
        }
    }

    const int node = row0 + w2 * 16 + (l & 15);
    if (node < n) {
        const int c0 = ((l >> 4) & 3) * 4;
#pragma unroll
        for (int nt = 0; nt < 8; ++nt) {
            union { short4 s4; __half h[4]; } pk;
#pragma unroll
            for (int r2 = 0; r2 < 4; ++r2) pk.h[r2] = __float2half(acc[nt][r2]);
            *(short4*)(C + (size_t)node * 128 + nt * 16 + c0) = pk.s4;
        }
    }
}

// fused: blocks [0, gH) run the packed-atomic histogram; blocks [gH, gH+gG)
// run gemm1. hist is atomic-latency-bound (VALU idle) -> gemm hides under it.
__global__ __launch_bounds__(256) void k_hist_gemm(
        u64* __restrict__ degcnt, const float* __restrict__ ew,
        const int* __restrict__ dst, unsigned short* __restrict__ rank,
        int e, int gH,
        const float* __restrict__ A, int lda, const __half* __restrict__ Wf,
        __half* __restrict__ C, int n) {
    __shared__ f16 AF[8192];
    const int bid = blockIdx.x;
    if (bid < gH) {
        int i0 = bid * 2048 + threadIdx.x;
#pragma unroll
        for (int u = 0; u < 8; ++u) {
            int i = i0 + u * 256;
            if (i < e) {
                unsigned fx = (unsigned)(ew[i] * 16777216.0f + 0.5f);
                u64 old = atomicAdd(&degcnt[dst[i]], ((u64)1 << 32) | (u64)fx);
                rank[i] = (unsigned short)(old >> 32);
            }
        }
    } else {
        gemm_body(A, lda, Wf, C, n, bid - gH, threadIdx.x, AF);
    }
}

__global__ __launch_bounds__(256) void k_gemm(const float* __restrict__ A, int lda,
                                              const __half* __restrict__ Wf,
                                              __half* __restrict__ C, int n) {
    __shared__ f16 AF[8192];
    gemm_body(A, lda, Wf, C, n, blockIdx.x, threadIdx.x, AF);
}

// fused: out[d, c] = relu( dis[d]^2 * hW[d,c] + sum_j norm_j * hW[src_j, c] + b[c] )
// one wave per dst node; lane handles features {2*lane, 2*lane+1}; x8 unroll.
__global__ __launch_bounds__(256) void k_agg(const __half* __restrict__ hW,
                                             const int2* __restrict__ ep,
                                             const int* __restrict__ rowstart,
                                             const float* __restrict__ dis,
                                             const float* __restrict__ bias,
                                             float* __restrict__ outcol,  // stride 256
                                             int n, int e) {
    int wid = blockIdx.x * 4 + (threadIdx.x >> 6);
    int lane = threadIdx.x & 63;
    if (wid >= n) return;

    int start = rowstart[wid];
    int end   = (wid == n - 1) ? e : rowstart[wid + 1];
    start = __builtin_amdgcn_readfirstlane(start);
    end   = __builtin_amdgcn_readfirstlane(end);

    float di = dis[wid];
    float2 h = __half22float2(*(const __half2*)(hW + (size_t)wid * 128 + lane * 2));
    float2 acc;
    acc.x = di * di * h.x;
    acc.y = di * di * h.y;

    int j = start;
    for (; j + 7 < end; j += 8) {
        int2 r[8];
        __half2 v[8];
#pragma unroll
        for (int u = 0; u < 8; ++u) r[u] = ep[j + u];
#pragma unroll
        for (int u = 0; u < 8; ++u)
            v[u] = *(const __half2*)(hW + (size_t)r[u].x * 128 + lane * 2);
#pragma unroll
        for (int u = 0; u < 8; ++u) {
            float nm = __int_as_float(r[u].y);
            float2 f = __half22float2(v[u]);
            acc.x += nm * f.x;
            acc.y += nm * f.y;
        }
    }
    for (; j < end; ++j) {
        int2 rec = ep[j];
        float nm = __int_as_float(rec.y);
        float2 v = __half22float2(*(const __half2*)(hW + (size_t)rec.x * 128 + lane * 2));
        acc.x += nm * v.x;
        acc.y += nm * v.y;
    }

    float2 b = *(const float2*)(bias + lane * 2);
    float2 o;
    o.x = fmaxf(acc.x + b.x, 0.f);
    o.y = fmaxf(acc.y + b.y, 0.f);
    *(float2*)(outcol + (size_t)wid * 256 + lane * 2) = o;
}

extern "C" void kernel_launch(void* const* d_in, const int* in_sizes, int n_in,
                              void* d_out, int out_size, void* d_ws, size_t ws_size,
                              hipStream_t stream) {
    const float* x  = (const float*)d_in[0];
    const float* ew = (const float*)d_in[1];
    const float* W0 = (const float*)d_in[2];
    const float* b0 = (const float*)d_in[3];
    const float* W1 = (const float*)d_in[4];
    const float* b1 = (const float*)d_in[5];
    const int*   ei = (const int*)d_in[6];

    const int N = in_sizes[0] / 128;
    const int E = in_sizes[1];
    const int* src = ei;
    const int* dst = ei + E;
    float* out = (float*)d_out;   // [N, 256]

    // ws layout (4B words), degcnt first for 8B alignment
    u64*   degcnt = (u64*)d_ws;
    float* dis    = (float*)(degcnt + N);
    int*   cursor = (int*)(dis + N);
    int2*  ep     = (int2*)(cursor + N);
    __half* hW    = (__half*)(ep + E);
    unsigned short* rank = (unsigned short*)((float*)hW + (size_t)N * 64);
    __half* Wf    = (__half*)((float*)hW + (size_t)N * 64 + (size_t)(E + 1) / 2);
    int*   sums   = (int*)((float*)Wf + 16384);   // 32768 halves = 16384 floats

    const int gN = (N + 255) / 256;
    const int gH = (E + 2047) / 2048;
    const int gG = (N + 63) / 64;
    const int gA = (N + 3) / 4;
    const int nb = gN;

    // ---- W fragment pack + CSR build; gemm1 fused under hist ----
    k_wfrag<<<16, 256, 0, stream>>>(W0, W1, Wf);
    k_init<<<gN, 256, 0, stream>>>(degcnt, N);
    k_hist_gemm<<<gH + gG, 256, 0, stream>>>(degcnt, ew, dst, rank, E, gH,
                                             x, 128, Wf, hW, N);
    k_dis<<<gN, 256, 0, stream>>>(degcnt, dis, cursor, N);
    k_scan1<<<nb, 256, 0, stream>>>(cursor, sums, N);
    k_scan2<<<1, 512, 0, stream>>>(sums, nb);
    k_scan3<<<nb, 256, 0, stream>>>(cursor, sums, N);
    k_scatter<<<gH, 256, 0, stream>>>(src, dst, ew, rank, dis, cursor, ep, E);
    // cursor holds row START pointers.

    // ---- layer 1 aggregation ----
    k_agg<<<gA, 256, 0, stream>>>(hW, ep, cursor, dis, b0, out, N, E);

    // ---- layer 2 ----
    k_gemm<<<gG, 256, 0, stream>>>(out, 256, Wf + 16384, hW, N);
    k_agg<<<gA, 256, 0, stream>>>(hW, ep, cursor, dis, b1, out + 128, N, E);
}

// Round 7
// 280.426 us; speedup vs baseline: 10.4005x; 1.0652x over previous
//
#include <hip/hip_runtime.h>
#include <hip/hip_fp16.h>

// ---------------------------------------------------------------------------
// GCN encoder, 2 layers, N=100000 D=H=128, E=1.6M.
// Round 7: (a) hist uses 256 grid-stride blocks so gemm1 blocks co-reside
//          (true overlap under the atomic-throughput-capped histogram);
//          (b) MFMA GEMM loads fragments direct-to-register (no LDS, no
//          barriers, no bank conflicts); (c) dis fused into scan1, init
//          fused with wfrag; (d) agg gather tiers 16/8/4/1.
// ws layout (4B words):
//   degcnt[2N] (u64) | dis[N] | cursor[N] | ep[2E] (int2) | hW[64N] (half)
//   | rank[E/2] (u16) | Wf[2*16384 halves] | sums[512]
// ---------------------------------------------------------------------------

typedef unsigned long long u64;
typedef _Float16 f16;
typedef f16 f16x8 __attribute__((ext_vector_type(8)));
typedef float f32x4 __attribute__((ext_vector_type(4)));

// setup: blocks [0,gN) init degcnt; blocks [gN,gN+16) pack W0,W1 fragments.
// Wf[sel][(ks*8+nt)*64 + l][j] = W[k(l,j)][nt*16 + (l&15)],
//   k(l,j) = ks*32 + ((l>>4)&3)*4 + (j&3) + 16*(j>>2)
__global__ __launch_bounds__(256) void k_setup(u64* degcnt, int n, int gN,
                                               const float* __restrict__ W0,
                                               const float* __restrict__ W1,
                                               __half* __restrict__ Wf) {
    int bid = blockIdx.x;
    if (bid < gN) {
        int i = bid * 256 + threadIdx.x;
        if (i < n) degcnt[i] = (u64)(1u << 24);   // deg=1.0 self-loop, count=0
    } else {
        int idx = (bid - gN) * 256 + threadIdx.x;     // 0..4095
        const float* W = (idx < 2048) ? W0 : W1;
        int id = idx & 2047;
        int l = id & 63, nt = (id >> 6) & 7, ks = id >> 9;
        int nn = nt * 16 + (l & 15);
        int kb = ks * 32 + ((l >> 4) & 3) * 4;
        union { int4 v; __half h[8]; } pk;
#pragma unroll
        for (int j = 0; j < 8; ++j) {
            int k = kb + (j & 3) + 16 * (j >> 2);
            pk.h[j] = __float2half(W[k * 128 + nn]);
        }
        *(int4*)(Wf + (size_t)idx * 8) = pk.v;
    }
}

// ---- MFMA f16 GEMM body: C[64 x 128] (fp16) = A(fp32) @ W (via Wf) ----
// Block = 4 waves; wave w owns nodes bid*64 + w*16 .. +15. No LDS.
__device__ __forceinline__ void gemm_body(const float* __restrict__ A, int lda,
                                          const __half* __restrict__ Wf,
                                          __half* __restrict__ C, int n,
                                          int bid, int t) {
    const int w2 = t >> 6, l = t & 63;
    const int node = bid * 64 + w2 * 16 + (l & 15);
    const int koff = ((l >> 4) & 3) * 4;
    const bool ok = node < n;
    const float* ap = A + (size_t)(ok ? node : 0) * lda;

    f16x8 af[4];
#pragma unroll
    for (int ks = 0; ks < 4; ++ks) {
        float4 a0 = make_float4(0.f, 0.f, 0.f, 0.f), a1 = a0;
        if (ok) {
            a0 = *(const float4*)(ap + ks * 32 + koff);
            a1 = *(const float4*)(ap + ks * 32 + koff + 16);
        }
        f16x8 h;
        h[0] = (f16)a0.x; h[1] = (f16)a0.y; h[2] = (f16)a0.z; h[3] = (f16)a0.w;
        h[4] = (f16)a1.x; h[5] = (f16)a1.y; h[6] = (f16)a1.z; h[7] = (f16)a1.w;
        af[ks] = h;
    }

    f32x4 acc[8];
#pragma unroll
    for (int i = 0; i < 8; ++i) acc[i] = (f32x4){0.f, 0.f, 0.f, 0.f};

#pragma unroll
    for (int ks = 0; ks < 4; ++ks) {
#pragma unroll
        for (int nt = 0; nt < 8; ++nt) {
            f16x8 wf = *(const f16x8*)(Wf + ((size_t)(ks * 8 + nt) * 64 + l) * 8);
            // D = (W^T-tile)(A^T-tile): D row = out-feature, D col = node
            acc[nt] = __builtin_amdgcn_mfma_f32_16x16x32_f16(wf, af[ks], acc[nt], 0, 0, 0);
        }
    }

    if (ok) {
        const int c0 = ((l >> 4) & 3) * 4;
#pragma unroll
        for (int nt = 0; nt < 8; ++nt) {
            union { short4 s4; __half h[4]; } pk;
#pragma unroll
            for (int r2 = 0; r2 < 4; ++r2) pk.h[r2] = __float2half(acc[nt][r2]);
            *(short4*)(C + (size_t)node * 128 + nt * 16 + c0) = pk.s4;
        }
    }
}

// fused: blocks [0,gH) grid-stride the packed-atomic histogram (gH=256 so
// gemm blocks co-reside and hide under the atomic throughput cap);
// blocks [gH, gH+gG) run gemm1.
__global__ __launch_bounds__(256) void k_hist_gemm(
        u64* __restrict__ degcnt, const float* __restrict__ ew,
        const int* __restrict__ dst, unsigned short* __restrict__ rank,
        int e, int gH,
        const float* __restrict__ A, int lda, const __half* __restrict__ Wf,
        __half* __restrict__ C, int n) {
    const int bid = blockIdx.x;
    if (bid < gH) {
        const int nch = (e + 2047) >> 11;
        for (int c = bid; c < nch; c += gH) {
            int i0 = c * 2048 + threadIdx.x;
#pragma unroll
            for (int u = 0; u < 8; ++u) {
                int i = i0 + u * 256;
                if (i < e) {
                    unsigned fx = (unsigned)(ew[i] * 16777216.0f + 0.5f);
                    u64 old = atomicAdd(&degcnt[dst[i]], ((u64)1 << 32) | (u64)fx);
                    rank[i] = (unsigned short)(old >> 32);
                }
            }
        }
    } else {
        gemm_body(A, lda, Wf, C, n, bid - gH, threadIdx.x);
    }
}

__global__ __launch_bounds__(256) void k_gemm(const float* __restrict__ A, int lda,
                                              const __half* __restrict__ Wf,
                                              __half* __restrict__ C, int n) {
    gemm_body(A, lda, Wf, C, n, blockIdx.x, threadIdx.x);
}

// scan1 + dis: v = count (hi32), dis = rsqrt(fixed24 deg), excl-scan counts
__global__ __launch_bounds__(256) void k_scan1(const u64* __restrict__ degcnt,
                                               float* __restrict__ dis,
                                               int* __restrict__ data,
                                               int* __restrict__ sums, int n) {
    __shared__ int tmp[256];
    int gid = blockIdx.x * 256 + threadIdx.x;
    int v = 0;
    if (gid < n) {
        u64 dc = degcnt[gid];
        float deg = (float)(unsigned)(dc & 0xffffffffull) * (1.0f / 16777216.0f);
        dis[gid] = rsqrtf(deg);
        v = (int)(dc >> 32);
    }
    tmp[threadIdx.x] = v;
    __syncthreads();
    for (int off = 1; off < 256; off <<= 1) {
        int t = (threadIdx.x >= off) ? tmp[threadIdx.x - off] : 0;
        __syncthreads();
        tmp[threadIdx.x] += t;
        __syncthreads();
    }
    if (gid < n) data[gid] = tmp[threadIdx.x] - v;
    if (threadIdx.x == 255) sums[blockIdx.x] = tmp[255];
}

__global__ __launch_bounds__(512) void k_scan2(int* sums, int nb) {
    __shared__ int tmp[512];
    int v = (threadIdx.x < nb) ? sums[threadIdx.x] : 0;
    tmp[threadIdx.x] = v;
    __syncthreads();
    for (int off = 1; off < 512; off <<= 1) {
        int t = (threadIdx.x >= off) ? tmp[threadIdx.x - off] : 0;
        __syncthreads();
        tmp[threadIdx.x] += t;
        __syncthreads();
    }
    if (threadIdx.x < nb) sums[threadIdx.x] = tmp[threadIdx.x] - v;
}

__global__ __launch_bounds__(256) void k_scan3(int* data, const int* sums, int n) {
    int gid = blockIdx.x * 256 + threadIdx.x;
    if (gid < n) data[gid] += sums[blockIdx.x];
}

// atomic-free scatter: pos = rowstart[dst] + rank
__global__ __launch_bounds__(256) void k_scatter(const int* __restrict__ src,
                                                 const int* __restrict__ dst,
                                                 const float* __restrict__ ew,
                                                 const unsigned short* __restrict__ rank,
                                                 const float* __restrict__ dis,
                                                 const int* __restrict__ rowstart,
                                                 int2* ep, int e) {
    int i0 = blockIdx.x * 2048 + threadIdx.x;
#pragma unroll
    for (int u = 0; u < 8; ++u) {
        int i = i0 + u * 256;
        if (i < e) {
            int s = src[i], d = dst[i];
            float nm = dis[s] * ew[i] * dis[d];
            int pos = rowstart[d] + (int)rank[i];
            ep[pos] = make_int2(s, __float_as_int(nm));
        }
    }
}

// fused: out[d,c] = relu( dis[d]^2*hW[d,c] + sum_j norm_j*hW[src_j,c] + b[c] )
// one wave per dst node; lane -> features {2*lane, 2*lane+1}; tiers 16/8/4/1.
__global__ __launch_bounds__(256) void k_agg(const __half* __restrict__ hW,
                                             const int2* __restrict__ ep,
                                             const int* __restrict__ rowstart,
                                             const float* __restrict__ dis,
                                             const float* __restrict__ bias,
                                             float* __restrict__ outcol,  // stride 256
                                             int n, int e) {
    int wid = blockIdx.x * 4 + (threadIdx.x >> 6);
    int lane = threadIdx.x & 63;
    if (wid >= n) return;

    int start = rowstart[wid];
    int end   = (wid == n - 1) ? e : rowstart[wid + 1];
    start = __builtin_amdgcn_readfirstlane(start);
    end   = __builtin_amdgcn_readfirstlane(end);

    float di = dis[wid];
    float2 h = __half22float2(*(const __half2*)(hW + (size_t)wid * 128 + lane * 2));
    float2 acc;
    acc.x = di * di * h.x;
    acc.y = di * di * h.y;

    int j = start;
    for (; j + 15 < end; j += 16) {
        int2 r[16];
        __half2 v[16];
#pragma unroll
        for (int u = 0; u < 16; ++u) r[u] = ep[j + u];
#pragma unroll
        for (int u = 0; u < 16; ++u)
            v[u] = *(const __half2*)(hW + (size_t)r[u].x * 128 + lane * 2);
#pragma unroll
        for (int u = 0; u < 16; ++u) {
            float nm = __int_as_float(r[u].y);
            float2 f = __half22float2(v[u]);
            acc.x += nm * f.x;
            acc.y += nm * f.y;
        }
    }
    for (; j + 7 < end; j += 8) {
        int2 r[8];
        __half2 v[8];
#pragma unroll
        for (int u = 0; u < 8; ++u) r[u] = ep[j + u];
#pragma unroll
        for (int u = 0; u < 8; ++u)
            v[u] = *(const __half2*)(hW + (size_t)r[u].x * 128 + lane * 2);
#pragma unroll
        for (int u = 0; u < 8; ++u) {
            float nm = __int_as_float(r[u].y);
            float2 f = __half22float2(v[u]);
            acc.x += nm * f.x;
            acc.y += nm * f.y;
        }
    }
    for (; j + 3 < end; j += 4) {
        int2 r[4];
        __half2 v[4];
#pragma unroll
        for (int u = 0; u < 4; ++u) r[u] = ep[j + u];
#pragma unroll
        for (int u = 0; u < 4; ++u)
            v[u] = *(const __half2*)(hW + (size_t)r[u].x * 128 + lane * 2);
#pragma unroll
        for (int u = 0; u < 4; ++u) {
            float nm = __int_as_float(r[u].y);
            float2 f = __half22float2(v[u]);
            acc.x += nm * f.x;
            acc.y += nm * f.y;
        }
    }
    for (; j < end; ++j) {
        int2 rec = ep[j];
        float nm = __int_as_float(rec.y);
        float2 v = __half22float2(*(const __half2*)(hW + (size_t)rec.x * 128 + lane * 2));
        acc.x += nm * v.x;
        acc.y += nm * v.y;
    }

    float2 b = *(const float2*)(bias + lane * 2);
    float2 o;
    o.x = fmaxf(acc.x + b.x, 0.f);
    o.y = fmaxf(acc.y + b.y, 0.f);
    *(float2*)(outcol + (size_t)wid * 256 + lane * 2) = o;
}

extern "C" void kernel_launch(void* const* d_in, const int* in_sizes, int n_in,
                              void* d_out, int out_size, void* d_ws, size_t ws_size,
                              hipStream_t stream) {
    const float* x  = (const float*)d_in[0];
    const float* ew = (const float*)d_in[1];
    const float* W0 = (const float*)d_in[2];
    const float* b0 = (const float*)d_in[3];
    const float* W1 = (const float*)d_in[4];
    const float* b1 = (const float*)d_in[5];
    const int*   ei = (const int*)d_in[6];

    const int N = in_sizes[0] / 128;
    const int E = in_sizes[1];
    const int* src = ei;
    const int* dst = ei + E;
    float* out = (float*)d_out;   // [N, 256]

    // ws layout (4B words), degcnt first for 8B alignment
    u64*   degcnt = (u64*)d_ws;
    float* dis    = (float*)(degcnt + N);
    int*   cursor = (int*)(dis + N);
    int2*  ep     = (int2*)(cursor + N);
    __half* hW    = (__half*)(ep + E);
    unsigned short* rank = (unsigned short*)((float*)hW + (size_t)N * 64);
    __half* Wf    = (__half*)((float*)hW + (size_t)N * 64 + (size_t)(E + 1) / 2);
    int*   sums   = (int*)((float*)Wf + 16384);   // 32768 halves = 16384 floats

    const int gN = (N + 255) / 256;
    const int gH = 256;                 // grid-stride hist blocks (1/CU)
    const int gE8 = (E + 2047) / 2048;
    const int gG = (N + 63) / 64;
    const int gA = (N + 3) / 4;
    const int nb = gN;

    // ---- setup (init degcnt + W fragment pack) ----
    k_setup<<<gN + 16, 256, 0, stream>>>(degcnt, N, gN, W0, W1, Wf);
    // ---- hist (atomic-capped) with gemm1 hidden under it ----
    k_hist_gemm<<<gH + gG, 256, 0, stream>>>(degcnt, ew, dst, rank, E, gH,
                                             x, 128, Wf, hW, N);
    k_scan1<<<nb, 256, 0, stream>>>(degcnt, dis, cursor, sums, N);
    k_scan2<<<1, 512, 0, stream>>>(sums, nb);
    k_scan3<<<nb, 256, 0, stream>>>(cursor, sums, N);
    k_scatter<<<gE8, 256, 0, stream>>>(src, dst, ew, rank, dis, cursor, ep, E);
    // cursor holds row START pointers.

    // ---- layer 1 aggregation ----
    k_agg<<<gA, 256, 0, stream>>>(hW, ep, cursor, dis, b0, out, N, E);

    // ---- layer 2 ----
    k_gemm<<<gG, 256, 0, stream>>>(out, 256, Wf + 16384, hW, N);
    k_agg<<<gA, 256, 0, stream>>>(hW, ep, cursor, dis, b1, out + 128, N, E);
}

// Round 9
// 269.434 us; speedup vs baseline: 10.8248x; 1.0408x over previous
//
#include <hip/hip_runtime.h>
#include <hip/hip_fp16.h>

// ---------------------------------------------------------------------------
// GCN encoder, 2 layers, N=100000 D=H=128, E=1.6M.
// Round 9 (= round 8 + launch-arg fix): atomic-free CSR build via two-level
// LDS counting sort.
//   p1: per-block LDS histogram by coarse bucket (dst>>9) -> H[bucket][block]
//   scan over H (bucket-major)  -> per-(bucket,block) base offsets
//   p2: scatter (src|low, w) records into bucket-grouped tmp (LDS ranks)
//   p3: one block per bucket: LDS per-node count + fixed-point weighted deg,
//       LDS scan -> rowstart + dis, cursor placement -> final ep (src, w).
//       gemm1 (MFMA) fused as extra blocks in the same dispatch.
//   agg: computes norm = dis[src]*w*dis[dst] inline (no norm-fixup pass).
// ws: H[NB*nch] | rowstart[N] | dis[N] | tmp[E] int2 | ep[E] int2
//     | hW[N*128] f16 | Wf[32768] f16 | sums[512]
// ---------------------------------------------------------------------------

typedef unsigned int u32;
typedef _Float16 f16;
typedef f16 f16x8 __attribute__((ext_vector_type(8)));
typedef float f32x4 __attribute__((ext_vector_type(4)));

// Pack W0,W1 (fp32 [128][128]) into MFMA fragment order:
// Wf[sel][(ks*8+nt)*64 + l][j] = W[k(l,j)][nt*16 + (l&15)],
//   k(l,j) = ks*32 + ((l>>4)&3)*4 + (j&3) + 16*(j>>2)
__global__ __launch_bounds__(256) void k_wfrag(const float* __restrict__ W0,
                                               const float* __restrict__ W1,
                                               __half* __restrict__ Wf) {
    int idx = blockIdx.x * 256 + threadIdx.x;     // 0..4095
    const float* W = (idx < 2048) ? W0 : W1;
    int id = idx & 2047;
    int l = id & 63, nt = (id >> 6) & 7, ks = id >> 9;
    int nn = nt * 16 + (l & 15);
    int kb = ks * 32 + ((l >> 4) & 3) * 4;
    union { int4 v; __half h[8]; } pk;
#pragma unroll
    for (int j = 0; j < 8; ++j) {
        int k = kb + (j & 3) + 16 * (j >> 2);
        pk.h[j] = __float2half(W[k * 128 + nn]);
    }
    *(int4*)(Wf + (size_t)idx * 8) = pk.v;
}

// phase 1: coarse histogram. block bid counts its 4096-edge chunk into LDS,
// writes H[bucket*nch + bid].
__global__ __launch_bounds__(256) void k_p1(const int* __restrict__ dst,
                                            u32* __restrict__ H,
                                            int e, int NB, int nch) {
    __shared__ u32 lcnt[512];
    const int t = threadIdx.x, bid = blockIdx.x;
    lcnt[t] = 0; lcnt[t + 256] = 0;
    __syncthreads();
    int i0 = bid * 4096 + t;
#pragma unroll
    for (int u = 0; u < 16; ++u) {
        int i = i0 + u * 256;
        if (i < e) atomicAdd(&lcnt[(u32)dst[i] >> 9], 1u);
    }
    __syncthreads();
    for (int b = t; b < NB; b += 256) H[(size_t)b * nch + bid] = lcnt[b];
}

// ---- exclusive scan (3-phase) over H[scanN] ----
__global__ __launch_bounds__(256) void k_scan1(u32* data, u32* sums, int n) {
    __shared__ u32 tmp[256];
    int gid = blockIdx.x * 256 + threadIdx.x;
    u32 v = (gid < n) ? data[gid] : 0;
    tmp[threadIdx.x] = v;
    __syncthreads();
    for (int off = 1; off < 256; off <<= 1) {
        u32 t = (threadIdx.x >= off) ? tmp[threadIdx.x - off] : 0;
        __syncthreads();
        tmp[threadIdx.x] += t;
        __syncthreads();
    }
    if (gid < n) data[gid] = tmp[threadIdx.x] - v;
    if (threadIdx.x == 255) sums[blockIdx.x] = tmp[255];
}

__global__ __launch_bounds__(512) void k_scan2(u32* sums, int nb) {
    __shared__ u32 tmp[512];
    u32 v = (threadIdx.x < nb) ? sums[threadIdx.x] : 0;
    tmp[threadIdx.x] = v;
    __syncthreads();
    for (int off = 1; off < 512; off <<= 1) {
        u32 t = (threadIdx.x >= off) ? tmp[threadIdx.x - off] : 0;
        __syncthreads();
        tmp[threadIdx.x] += t;
        __syncthreads();
    }
    if (threadIdx.x < nb) sums[threadIdx.x] = tmp[threadIdx.x] - v;
}

__global__ __launch_bounds__(256) void k_scan3(u32* data, const u32* sums, int n) {
    int gid = blockIdx.x * 256 + threadIdx.x;
    if (gid < n) data[gid] += sums[blockIdx.x];
}

// phase 2: scatter records into bucket-grouped tmp. pos = H'[b][bid] + LDS rank.
// record: x = src | (dst&511)<<17 ; y = w bits.
__global__ __launch_bounds__(256) void k_p2(const int* __restrict__ src,
                                            const int* __restrict__ dst,
                                            const float* __restrict__ w,
                                            const u32* __restrict__ H,
                                            int2* __restrict__ tmp,
                                            int e, int NB, int nch) {
    __shared__ u32 lcnt[512];
    __shared__ u32 lbase[512];
    const int t = threadIdx.x, bid = blockIdx.x;
    lcnt[t] = 0; lcnt[t + 256] = 0;
    __syncthreads();
    for (int b = t; b < NB; b += 256) lbase[b] = H[(size_t)b * nch + bid];
    __syncthreads();
    int i0 = bid * 4096 + t;
#pragma unroll
    for (int u = 0; u < 16; ++u) {
        int i = i0 + u * 256;
        if (i < e) {
            int d = dst[i];
            u32 b = (u32)d >> 9;
            u32 lr = atomicAdd(&lcnt[b], 1u);
            tmp[lbase[b] + lr] = make_int2(src[i] | ((d & 511) << 17),
                                           __float_as_int(w[i]));
        }
    }
}

// ---- MFMA f16 GEMM body: C[64 x 128] (fp16) = A(fp32) @ W (via Wf) ----
// 256-thread group = 4 waves; wave w owns nodes bid*64 + w*16 .. +15. No LDS.
__device__ __forceinline__ void gemm_body(const float* __restrict__ A, int lda,
                                          const __half* __restrict__ Wf,
                                          __half* __restrict__ C, int n,
                                          int bid, int t) {
    const int w2 = t >> 6, l = t & 63;
    const int node = bid * 64 + w2 * 16 + (l & 15);
    const int koff = ((l >> 4) & 3) * 4;
    const bool ok = node < n;
    const float* ap = A + (size_t)(ok ? node : 0) * lda;

    f16x8 af[4];
#pragma unroll
    for (int ks = 0; ks < 4; ++ks) {
        float4 a0 = make_float4(0.f, 0.f, 0.f, 0.f), a1 = a0;
        if (ok) {
            a0 = *(const float4*)(ap + ks * 32 + koff);
            a1 = *(const float4*)(ap + ks * 32 + koff + 16);
        }
        f16x8 h;
        h[0] = (f16)a0.x; h[1] = (f16)a0.y; h[2] = (f16)a0.z; h[3] = (f16)a0.w;
        h[4] = (f16)a1.x; h[5] = (f16)a1.y; h[6] = (f16)a1.z; h[7] = (f16)a1.w;
        af[ks] = h;
    }

    f32x4 acc[8];
#pragma unroll
    for (int i = 0; i < 8; ++i) acc[i] = (f32x4){0.f, 0.f, 0.f, 0.f};

#pragma unroll
    for (int ks = 0; ks < 4; ++ks) {
#pragma unroll
        for (int nt = 0; nt < 8; ++nt) {
            f16x8 wf = *(const f16x8*)(Wf + ((size_t)(ks * 8 + nt) * 64 + l) * 8);
            acc[nt] = __builtin_amdgcn_mfma_f32_16x16x32_f16(wf, af[ks], acc[nt], 0, 0, 0);
        }
    }

    if (ok) {
        const int c0 = ((l >> 4) & 3) * 4;
#pragma unroll
        for (int nt = 0; nt < 8; ++nt) {
            union { short4 s4; __half h[4]; } pk;
#pragma unroll
            for (int r2 = 0; r2 < 4; ++r2) pk.h[r2] = __float2half(acc[nt][r2]);
            *(short4*)(C + (size_t)node * 128 + nt * 16 + c0) = pk.s4;
        }
    }
}

// phase 3: blocks [0,NB): fine counting-sort of one bucket (512 nodes):
//   per-node count + fixed-point weighted deg (LDS), LDS scan -> rowstart/dis,
//   cursor placement -> ep (clean src, w).
// blocks [NB, NB+gemmB): gemm1 tiles (2 per 512-thread block).
__global__ __launch_bounds__(512) void k_p3(const int2* __restrict__ tmp,
                                            const u32* __restrict__ H,
                                            int2* __restrict__ ep,
                                            int* __restrict__ rowstart,
                                            float* __restrict__ dis,
                                            int e, int n, int NB, int nch,
                                            const float* __restrict__ A, int lda,
                                            const __half* __restrict__ Wf,
                                            __half* __restrict__ C) {
    const int bid = blockIdx.x, t = threadIdx.x;
    if (bid >= NB) {
        int g = bid - NB;
        gemm_body(A, lda, Wf, C, n, g * 2 + (t >> 8), t & 255);
        return;
    }
    __shared__ u32 cnt[512];
    __shared__ u32 degx[512];
    __shared__ u32 off[512];
    __shared__ u32 stmp[512];

    cnt[t] = 0; degx[t] = 0;
    __syncthreads();

    const int bs = (int)H[(size_t)bid * nch];
    const int be = (bid + 1 < NB) ? (int)H[(size_t)(bid + 1) * nch] : e;

    for (int j = bs + t; j < be; j += 512) {
        int2 r = tmp[j];
        u32 low = ((u32)r.x >> 17) & 511u;
        atomicAdd(&cnt[low], 1u);
        atomicAdd(&degx[low], (u32)(__int_as_float(r.y) * 1048576.0f + 0.5f));
    }
    __syncthreads();

    u32 v = cnt[t];
    stmp[t] = v;
    __syncthreads();
    for (int o = 1; o < 512; o <<= 1) {
        u32 x = (t >= o) ? stmp[t - o] : 0u;
        __syncthreads();
        stmp[t] += x;
        __syncthreads();
    }
    off[t] = stmp[t] - v;

    const int node = bid * 512 + t;
    if (node < n) {
        rowstart[node] = bs + (int)off[t];
        dis[node] = rsqrtf(1.0f + (float)degx[t] * (1.0f / 1048576.0f));
    }
    __syncthreads();

    for (int j = bs + t; j < be; j += 512) {
        int2 r = tmp[j];
        u32 low = ((u32)r.x >> 17) & 511u;
        u32 p = atomicAdd(&off[low], 1u);
        ep[bs + p] = make_int2(r.x & 0x1FFFF, r.y);
    }
}

__global__ __launch_bounds__(256) void k_gemm(const float* __restrict__ A, int lda,
                                              const __half* __restrict__ Wf,
                                              __half* __restrict__ C, int n) {
    gemm_body(A, lda, Wf, C, n, blockIdx.x, threadIdx.x);
}

// fused: out[d,c] = relu( dis[d]^2*hW[d,c] + sum_j dis[s]*w*dis[d]*hW[s,c] + b[c] )
// one wave per dst node; lane -> features {2*lane, 2*lane+1}; tiers 16/8/4/1.
// ep records are (src, w); norm computed inline.
__global__ __launch_bounds__(256) void k_agg(const __half* __restrict__ hW,
                                             const int2* __restrict__ ep,
                                             const int* __restrict__ rowstart,
                                             const float* __restrict__ dis,
                                             const float* __restrict__ bias,
                                             float* __restrict__ outcol,  // stride 256
                                             int n, int e) {
    int wid = blockIdx.x * 4 + (threadIdx.x >> 6);
    int lane = threadIdx.x & 63;
    if (wid >= n) return;

    int start = rowstart[wid];
    int end   = (wid == n - 1) ? e : rowstart[wid + 1];
    start = __builtin_amdgcn_readfirstlane(start);
    end   = __builtin_amdgcn_readfirstlane(end);

    float dd = dis[wid];
    float2 h = __half22float2(*(const __half2*)(hW + (size_t)wid * 128 + lane * 2));
    float2 acc;
    acc.x = dd * dd * h.x;
    acc.y = dd * dd * h.y;

    int j = start;
    for (; j + 15 < end; j += 16) {
        int2 r[16];
        float ds[16];
        __half2 v[16];
#pragma unroll
        for (int u = 0; u < 16; ++u) r[u] = ep[j + u];
#pragma unroll
        for (int u = 0; u < 16; ++u) ds[u] = dis[r[u].x];
#pragma unroll
        for (int u = 0; u < 16; ++u)
            v[u] = *(const __half2*)(hW + (size_t)r[u].x * 128 + lane * 2);
#pragma unroll
        for (int u = 0; u < 16; ++u) {
            float nm = ds[u] * __int_as_float(r[u].y) * dd;
            float2 f = __half22float2(v[u]);
            acc.x += nm * f.x;
            acc.y += nm * f.y;
        }
    }
    for (; j + 7 < end; j += 8) {
        int2 r[8];
        float ds[8];
        __half2 v[8];
#pragma unroll
        for (int u = 0; u < 8; ++u) r[u] = ep[j + u];
#pragma unroll
        for (int u = 0; u < 8; ++u) ds[u] = dis[r[u].x];
#pragma unroll
        for (int u = 0; u < 8; ++u)
            v[u] = *(const __half2*)(hW + (size_t)r[u].x * 128 + lane * 2);
#pragma unroll
        for (int u = 0; u < 8; ++u) {
            float nm = ds[u] * __int_as_float(r[u].y) * dd;
            float2 f = __half22float2(v[u]);
            acc.x += nm * f.x;
            acc.y += nm * f.y;
        }
    }
    for (; j + 3 < end; j += 4) {
        int2 r[4];
        float ds[4];
        __half2 v[4];
#pragma unroll
        for (int u = 0; u < 4; ++u) r[u] = ep[j + u];
#pragma unroll
        for (int u = 0; u < 4; ++u) ds[u] = dis[r[u].x];
#pragma unroll
        for (int u = 0; u < 4; ++u)
            v[u] = *(const __half2*)(hW + (size_t)r[u].x * 128 + lane * 2);
#pragma unroll
        for (int u = 0; u < 4; ++u) {
            float nm = ds[u] * __int_as_float(r[u].y) * dd;
            float2 f = __half22float2(v[u]);
            acc.x += nm * f.x;
            acc.y += nm * f.y;
        }
    }
    for (; j < end; ++j) {
        int2 rec = ep[j];
        float nm = dis[rec.x] * __int_as_float(rec.y) * dd;
        float2 v = __half22float2(*(const __half2*)(hW + (size_t)rec.x * 128 + lane * 2));
        acc.x += nm * v.x;
        acc.y += nm * v.y;
    }

    float2 b = *(const float2*)(bias + lane * 2);
    float2 o;
    o.x = fmaxf(acc.x + b.x, 0.f);
    o.y = fmaxf(acc.y + b.y, 0.f);
    *(float2*)(outcol + (size_t)wid * 256 + lane * 2) = o;
}

extern "C" void kernel_launch(void* const* d_in, const int* in_sizes, int n_in,
                              void* d_out, int out_size, void* d_ws, size_t ws_size,
                              hipStream_t stream) {
    const float* x  = (const float*)d_in[0];
    const float* ew = (const float*)d_in[1];
    const float* W0 = (const float*)d_in[2];
    const float* b0 = (const float*)d_in[3];
    const float* W1 = (const float*)d_in[4];
    const float* b1 = (const float*)d_in[5];
    const int*   ei = (const int*)d_in[6];

    const int N = in_sizes[0] / 128;
    const int E = in_sizes[1];
    const int* src = ei;
    const int* dst = ei + E;
    float* out = (float*)d_out;   // [N, 256]

    const int NB  = (N + 511) >> 9;          // 196 coarse buckets
    const int nch = (E + 4095) >> 12;        // 391 phase blocks
    const int scanN = NB * nch;              // 76636
    const int scanB = (scanN + 255) / 256;   // 300
    const int gT = (N + 63) / 64;            // gemm tiles (1563)
    const int gemmB = (gT + 1) / 2;          // 512-thread gemm blocks in p3
    const int gA = (N + 3) / 4;

    // ws layout (4B words, keep 8B alignment for int2)
    const size_t Hsz = (size_t)((scanN + 1) & ~1);
    const size_t Npad = (size_t)((N + 1) & ~1);
    u32*   H        = (u32*)d_ws;
    int*   rowstart = (int*)(H + Hsz);
    float* dis      = (float*)(rowstart + Npad);
    int2*  tmp      = (int2*)(dis + Npad);
    int2*  ep       = tmp + E;
    __half* hW      = (__half*)(ep + E);
    __half* Wf      = hW + (size_t)N * 128;
    u32*   sums     = (u32*)(Wf + 32768);

    // ---- build ----
    k_wfrag<<<16, 256, 0, stream>>>(W0, W1, Wf);
    k_p1<<<nch, 256, 0, stream>>>(dst, H, E, NB, nch);
    k_scan1<<<scanB, 256, 0, stream>>>(H, sums, scanN);
    k_scan2<<<1, 512, 0, stream>>>(sums, scanB);
    k_scan3<<<scanB, 256, 0, stream>>>(H, sums, scanN);
    k_p2<<<nch, 256, 0, stream>>>(src, dst, ew, H, tmp, E, NB, nch);
    k_p3<<<NB + gemmB, 512, 0, stream>>>(tmp, H, ep, rowstart, dis, E, N, NB, nch,
                                         x, 128, Wf, hW);

    // ---- layer 1 aggregation ----
    k_agg<<<gA, 256, 0, stream>>>(hW, ep, rowstart, dis, b0, out, N, E);

    // ---- layer 2 ----
    k_gemm<<<gT, 256, 0, stream>>>(out, 256, Wf + 16384, hW, N);
    k_agg<<<gA, 256, 0, stream>>>(hW, ep, rowstart, dis, b1, out + 128, N, E);
}